// Round 9
// baseline (2089.623 us; speedup 1.0000x reference)
//
#include <hip/hip_runtime.h>
#include <hip/hip_bf16.h>
#include <math.h>

#define B_ 4
#define N_ 2048
#define D_ 1024
#define WIN_ 4
#define KTOP 8
#define ALPHA_ 0.3f
#define SCALE_ (1.0f/32.0f)
#define NCH 16          // N_/128 col chunks
#define TROW 36         // ushorts per LDS tile row (72B stride, conflict-free)

typedef unsigned short ushortT;
typedef __attribute__((ext_vector_type(8))) short short8v;   // 8 bf16 (4 VGPR)
typedef __attribute__((ext_vector_type(4))) float f32x4;

__device__ inline ushortT f2b(float f) {     // f32 -> bf16 RNE
    unsigned int u = __float_as_uint(f);
    unsigned int r = (u + 0x7fffu + ((u >> 16) & 1u)) >> 16;
    return (ushortT)r;
}
__device__ inline float b2f(ushortT u) {
    return __uint_as_float(((unsigned int)u) << 16);
}

// ---------------------------------------------------------------------------
// mu f32 -> 3 bf16 planes: a contiguous, b contiguous, c STRIDED into CCb's
// right half (row*2048 + 1024 + col).
// ---------------------------------------------------------------------------
__global__ __launch_bounds__(256)
void split3_mu(const float* __restrict__ src, ushortT* __restrict__ Pa,
               ushortT* __restrict__ Pb, ushortT* __restrict__ CCbase)
{
    size_t base = ((size_t)blockIdx.x * 256 + threadIdx.x) * 4;
    int row = (int)(base >> 10);
    int col = (int)(base & 1023);
    float4 v = *reinterpret_cast<const float4*>(&src[base]);
    ushort4 pa, pb, pc;
    float vv[4] = {v.x, v.y, v.z, v.w};
#pragma unroll
    for (int j = 0; j < 4; ++j) {
        float f = vv[j];
        ushortT a = f2b(f);  float r1 = f - b2f(a);
        ushortT b = f2b(r1); float r2 = r1 - b2f(b);
        ushortT c = f2b(r2);
        ((ushortT*)&pa)[j] = a; ((ushortT*)&pb)[j] = b; ((ushortT*)&pc)[j] = c;
    }
    *reinterpret_cast<ushort4*>(&Pa[base]) = pa;
    *reinterpret_cast<ushort4*>(&Pb[base]) = pb;
    *reinterpret_cast<ushort4*>(&CCbase[(size_t)row * 2048 + 1024 + col]) = pc;
}

// ---------------------------------------------------------------------------
// W [K][Nn] f32 -> Wt [Nn][K] bf16 (single plane)
// ---------------------------------------------------------------------------
__global__ __launch_bounds__(256)
void transpose_f2b(const float* __restrict__ W, ushortT* __restrict__ Wt,
                   int K, int Nn)
{
    __shared__ float t[32][33];
    const int k0 = blockIdx.x * 32, n0 = blockIdx.y * 32;
    const int tx = threadIdx.x & 31, ty8 = threadIdx.x >> 5;
#pragma unroll
    for (int p = 0; p < 4; ++p) {
        int kk = p * 8 + ty8;
        t[kk][tx] = W[(size_t)(k0 + kk) * Nn + n0 + tx];
    }
    __syncthreads();
#pragma unroll
    for (int p = 0; p < 4; ++p) {
        int nn = p * 8 + ty8;
        Wt[(size_t)(n0 + nn) * K + k0 + tx] = f2b(t[tx][nn]);
    }
}

// ---------------------------------------------------------------------------
// W [K][Nn] f32 -> 3 transposed bf16 planes [Nn][K]
// ---------------------------------------------------------------------------
__global__ __launch_bounds__(256)
void transpose_split3(const float* __restrict__ W, ushortT* __restrict__ Pa,
                      ushortT* __restrict__ Pb, ushortT* __restrict__ Pc,
                      int K, int Nn)
{
    __shared__ float t[32][33];
    const int k0 = blockIdx.x * 32, n0 = blockIdx.y * 32;
    const int tx = threadIdx.x & 31, ty8 = threadIdx.x >> 5;
#pragma unroll
    for (int p = 0; p < 4; ++p) {
        int kk = p * 8 + ty8;
        t[kk][tx] = W[(size_t)(k0 + kk) * Nn + n0 + tx];
    }
    __syncthreads();
#pragma unroll
    for (int p = 0; p < 4; ++p) {
        int nn = p * 8 + ty8;
        float f = t[tx][nn];
        ushortT a = f2b(f);  float r1 = f - b2f(a);
        ushortT b = f2b(r1); float r2 = r1 - b2f(b);
        ushortT c = f2b(r2);
        size_t o = (size_t)(n0 + nn) * K + k0 + tx;
        Pa[o] = a; Pb[o] = b; Pc[o] = c;
    }
}

// ---------------------------------------------------------------------------
// bf16 MFMA GEMM (proven): 128x128 tile, BK=64, 4 waves, 64x64/wave.
// ---------------------------------------------------------------------------
template<int BF16OUT>
__global__ __launch_bounds__(256)
void mfma_gemm(const ushortT* __restrict__ A, int lda,
               const ushortT* __restrict__ Bt, int ldb,
               const float* __restrict__ bias,
               void* __restrict__ Cout, int ldc, int K)
{
    __shared__ ushortT AsL[128 * 72];
    __shared__ ushortT BsL[128 * 72];
    const int tid = threadIdx.x;
    const int m0 = blockIdx.y * 128;
    const int n0 = blockIdx.x * 128;
    const int w = tid >> 6, lane = tid & 63;
    const int wr = w >> 1, wc = w & 1;

    f32x4 acc[4][4];
#pragma unroll
    for (int mi = 0; mi < 4; ++mi)
#pragma unroll
        for (int ni = 0; ni < 4; ++ni) acc[mi][ni] = (f32x4){0.f, 0.f, 0.f, 0.f};

    for (int k0 = 0; k0 < K; k0 += 64) {
#pragma unroll
        for (int it = 0; it < 4; ++it) {
            int idx = tid + it * 256;        // 0..1023
            int row = idx >> 3, c = idx & 7;
            int4 va = *reinterpret_cast<const int4*>(&A[(size_t)(m0 + row) * lda + k0 + c * 8]);
            *reinterpret_cast<int4*>(&AsL[row * 72 + c * 8]) = va;
            int4 vb = *reinterpret_cast<const int4*>(&Bt[(size_t)(n0 + row) * ldb + k0 + c * 8]);
            *reinterpret_cast<int4*>(&BsL[row * 72 + c * 8]) = vb;
        }
        __syncthreads();
#pragma unroll
        for (int kh = 0; kh < 2; ++kh) {
            const int ko = kh * 32 + (lane >> 4) * 8;
            const int rr = lane & 15;
            short8v af[4], bf[4];
#pragma unroll
            for (int mi = 0; mi < 4; ++mi)
                af[mi] = *reinterpret_cast<const short8v*>(&AsL[(wr * 64 + mi * 16 + rr) * 72 + ko]);
#pragma unroll
            for (int ni = 0; ni < 4; ++ni)
                bf[ni] = *reinterpret_cast<const short8v*>(&BsL[(wc * 64 + ni * 16 + rr) * 72 + ko]);
#pragma unroll
            for (int mi = 0; mi < 4; ++mi)
#pragma unroll
                for (int ni = 0; ni < 4; ++ni)
                    acc[mi][ni] = __builtin_amdgcn_mfma_f32_16x16x32_bf16(
                        af[mi], bf[ni], acc[mi][ni], 0, 0, 0);
        }
        __syncthreads();
    }

    const int r4 = (lane >> 4) * 4, cl = lane & 15;
#pragma unroll
    for (int mi = 0; mi < 4; ++mi)
#pragma unroll
        for (int ni = 0; ni < 4; ++ni) {
            int row = m0 + wr * 64 + mi * 16 + r4;
            int col = n0 + wc * 64 + ni * 16 + cl;
            float bb = bias ? bias[col] : 0.f;
#pragma unroll
            for (int r = 0; r < 4; ++r) {
                float v = acc[mi][ni][r] + bb;
                if (BF16OUT)
                    ((ushortT*)Cout)[(size_t)(row + r) * ldc + col] = f2b(v);
                else
                    ((float*)Cout)[(size_t)(row + r) * ldc + col] = v;
            }
        }
}

// ---------------------------------------------------------------------------
// S[b,n,:] = mean_w silu(A + Nb shifted), output bf16.
// ---------------------------------------------------------------------------
__global__ __launch_bounds__(256)
void silu_mean(const float* __restrict__ A, const float* __restrict__ Nb,
               ushortT* __restrict__ Sb)
{
    size_t idx4 = (size_t)blockIdx.x * blockDim.x + threadIdx.x;
    size_t base = idx4 << 2;
    int n = (int)((base >> 10) & (N_ - 1));
    float4 a = *reinterpret_cast<const float4*>(&A[base]);
    float sx = 0.f, sy = 0.f, sz = 0.f, sw = 0.f;
#pragma unroll
    for (int w = 1; w <= WIN_; ++w) {
        float xx = a.x, xy = a.y, xz = a.z, xw = a.w;
        if (n >= w) {
            const float4 nb = *reinterpret_cast<const float4*>(&Nb[base - (size_t)w * D_]);
            xx += nb.x; xy += nb.y; xz += nb.z; xw += nb.w;
        }
        sx += xx / (1.f + __expf(-xx));
        sy += xy / (1.f + __expf(-xy));
        sz += xz / (1.f + __expf(-xz));
        sw += xw / (1.f + __expf(-xw));
    }
    ushort4 o = {f2b(sx * 0.25f), f2b(sy * 0.25f), f2b(sz * 0.25f), f2b(sw * 0.25f)};
    *reinterpret_cast<ushort4*>(&Sb[base]) = o;
}

// ---------------------------------------------------------------------------
__device__ inline void topk_insert(float (&tv)[KTOP], int (&ti)[KTOP], float s, int m)
{
    if ((s > tv[KTOP-1]) || (s == tv[KTOP-1] && m < ti[KTOP-1])) {
        float cs = s; int ci = m;
#pragma unroll
        for (int q = 0; q < KTOP; ++q) {
            bool beats = (cs > tv[q]) || (cs == tv[q] && ci < ti[q]);
            if (beats) { float t0 = tv[q]; int t1 = ti[q];
                         tv[q] = cs; ti[q] = ci; cs = t0; ci = t1; }
        }
    }
}

// ---------------------------------------------------------------------------
// 6-product split-MFMA core (R7-proven shape): 8 waves, wave tile 64x32
// (wr in {0,1}, wc in {0..3}), acc[4][2]. Products p+q<=2 (ah,al,am,bh,bl,ch).
// Tb = base of the current LDS buffer (6 planes x 128 x TROW).
// ---------------------------------------------------------------------------
#define SPLIT6_COMPUTE(Tb, wr, wc, lane, acc)                                   \
    {                                                                           \
        const int rr_ = (lane) & 15, ko_ = ((lane) >> 4) * 8;                   \
        _Pragma("unroll")                                                       \
        for (int p_ = 0; p_ < 3; ++p_) {                                        \
            short8v aF_[4];                                                     \
            _Pragma("unroll")                                                   \
            for (int mi_ = 0; mi_ < 4; ++mi_)                                   \
                aF_[mi_] = *reinterpret_cast<const short8v*>(                   \
                    &Tb[p_ * 4608 + ((wr) * 64 + mi_ * 16 + rr_) * TROW + ko_]);\
            _Pragma("unroll")                                                   \
            for (int q_ = 0; q_ < 3; ++q_) {                                    \
                if (p_ + q_ > 2) continue;                                      \
                short8v b0_ = *reinterpret_cast<const short8v*>(                \
                    &Tb[(3 + q_) * 4608 + ((wc) * 32 + rr_) * TROW + ko_]);     \
                short8v b1_ = *reinterpret_cast<const short8v*>(                \
                    &Tb[(3 + q_) * 4608 + ((wc) * 32 + 16 + rr_) * TROW + ko_]);\
                _Pragma("unroll")                                               \
                for (int mi_ = 0; mi_ < 4; ++mi_) {                             \
                    acc[mi_][0] = __builtin_amdgcn_mfma_f32_16x16x32_bf16(      \
                        aF_[mi_], b0_, acc[mi_][0], 0, 0, 0);                   \
                    acc[mi_][1] = __builtin_amdgcn_mfma_f32_16x16x32_bf16(      \
                        aF_[mi_], b1_, acc[mi_][1], 0, 0, 0);                   \
                }                                                               \
            }                                                                   \
        }                                                                       \
    }

// stage: 512 threads, each thread one 16B chunk per plane (6 int4 regs).
#define S6_LOAD(kk)                                                             \
    {                                                                           \
        s[0] = *reinterpret_cast<const int4*>(&P0_[oA_ + (kk)]);                \
        s[1] = *reinterpret_cast<const int4*>(&P1_[oA_ + (kk)]);                \
        s[2] = *reinterpret_cast<const int4*>(&P2_[oAc_ + (kk)]);               \
        s[3] = *reinterpret_cast<const int4*>(&P3_[oB_ + (kk)]);                \
        s[4] = *reinterpret_cast<const int4*>(&P4_[oB_ + (kk)]);                \
        s[5] = *reinterpret_cast<const int4*>(&P5_[oB_ + (kk)]);                \
    }
#define S6_STORE(bufsel)                                                        \
    {                                                                           \
        ushortT* Tb_ = &T6[(bufsel)][0];                                        \
        _Pragma("unroll")                                                       \
        for (int t_ = 0; t_ < 6; ++t_)                                          \
            *reinterpret_cast<int4*>(&Tb_[t_ * 4608 + ldst]) = s[t_];           \
    }

// ---------------------------------------------------------------------------
// gemm_split6: out = (A0+A1+A2) @ (B0+B1+B2)^T + bias, 6 kept products,
// f32-equivalent. 512 thr / 8 waves / 64x32 wave tile (R7-proven), now with
// LDS DOUBLE-BUFFER + single barrier per K-step. Output: 3 bf16 planes.
// ---------------------------------------------------------------------------
__global__ __launch_bounds__(512, 4)
void gemm_split6(const ushortT* __restrict__ A0, const ushortT* __restrict__ A1,
                 const ushortT* __restrict__ A2, int lda, int ldac,
                 const ushortT* __restrict__ B0, const ushortT* __restrict__ B1,
                 const ushortT* __restrict__ B2,
                 const float* __restrict__ bias,
                 ushortT* __restrict__ Pa, ushortT* __restrict__ Pb,
                 ushortT* __restrict__ Pc)
{
    __shared__ ushortT T6[2][6 * 128 * TROW];          // 2 x 55296 B

    int lin = blockIdx.y * 8 + blockIdx.x;             // 0..511
    lin = (lin & 7) * 64 + (lin >> 3);                 // XCD-chunked
    const int m0 = (lin >> 3) * 128;
    const int n0 = (lin & 7) * 128;

    const int tid = threadIdx.x;
    const int wid = tid >> 6, lane = tid & 63;
    const int wr = wid >> 2, wc = wid & 3;
    const int rowL = tid >> 2, cL = tid & 3;

    const ushortT *P0_ = A0, *P1_ = A1, *P2_ = A2, *P3_ = B0, *P4_ = B1, *P5_ = B2;
    const size_t oA_  = (size_t)(m0 + rowL) * lda + cL * 8;
    const size_t oAc_ = (size_t)(m0 + rowL) * ldac + cL * 8;
    const size_t oB_  = (size_t)(n0 + rowL) * D_ + cL * 8;
    const int ldst = rowL * TROW + cL * 8;

    f32x4 acc[4][2];
#pragma unroll
    for (int mi = 0; mi < 4; ++mi) { acc[mi][0] = (f32x4){0,0,0,0}; acc[mi][1] = (f32x4){0,0,0,0}; }

    int4 s[6];
    S6_LOAD(0)
    S6_STORE(0)
    S6_LOAD(32)

    for (int ks = 0; ks < 32; ++ks) {
        __syncthreads();                  // buf[ks&1] stores visible; buf^1 free
        if (ks < 31) S6_STORE((ks + 1) & 1)
        if (ks < 30) S6_LOAD((ks + 2) * 32)
        const ushortT* Tb = &T6[ks & 1][0];
        SPLIT6_COMPUTE(Tb, wr, wc, lane, acc)
    }

    const int r4 = (lane >> 4) * 4, cl = lane & 15;
#pragma unroll
    for (int mi = 0; mi < 4; ++mi)
#pragma unroll
        for (int ni = 0; ni < 2; ++ni) {
            int col = n0 + wc * 32 + ni * 16 + cl;
            float bb = bias[col];
#pragma unroll
            for (int r = 0; r < 4; ++r) {
                int row = m0 + wr * 64 + mi * 16 + r4 + r;
                float v = acc[mi][ni][r] + bb;
                ushortT a = f2b(v);  float r1 = v - b2f(a);
                ushortT b = f2b(r1); float r2 = r1 - b2f(b);
                ushortT c = f2b(r2);
                size_t o = (size_t)row * D_ + col;
                Pa[o] = a; Pb[o] = b; Pc[o] = c;
            }
        }
}

// ---------------------------------------------------------------------------
// attn_scores_mfma2: 6-product split scores + mask + pheromone + per-chunk
// top-8. 512 thr / 8 waves / 64x32 wave tile, LDS dbuf + 1 barrier/K-step.
// ---------------------------------------------------------------------------
__global__ __launch_bounds__(512, 4)
void attn_scores_mfma2(const ushortT* __restrict__ Qa, const ushortT* __restrict__ Qb2,
                       const ushortT* __restrict__ Qc,
                       const ushortT* __restrict__ Ka, const ushortT* __restrict__ Kb2,
                       const ushortT* __restrict__ Kc,
                       const float* __restrict__ pher,
                       float* __restrict__ WV, int* __restrict__ WI)
{
    __shared__ ushortT T6[2][6 * 128 * TROW];          // 2 x 55296 B
    __shared__ float Ps[128];
    float* MV = reinterpret_cast<float*>(&T6[0][0]);                 // [32][128]
    int*   MI = reinterpret_cast<int*>((char*)&T6[0][0] + 16384);    // [32][128]
    float* PV = reinterpret_cast<float*>((char*)&T6[0][0] + 32768);  // [32][4][8]
    int*   PI = reinterpret_cast<int*>((char*)&T6[0][0] + 36864);    // [32][4][8]

    int lin = blockIdx.y * 136 + blockIdx.x;           // 0..543
    lin = (lin & 7) * 68 + (lin >> 3);                 // XCD-chunked, 544=8*68
    const int b = lin / 136;
    const int xy = lin - b * 136;
    int g = 0;
    while ((g + 1) * (g + 2) / 2 <= xy) ++g;
    const int ch = xy - g * (g + 1) / 2;
    const int n0 = g * 128;
    const int m0 = ch * 128;
    const size_t bN = (size_t)b * N_;

    const int tid = threadIdx.x;
    const int wid = tid >> 6, lane = tid & 63;
    const int wr = wid >> 2, wc = wid & 3;
    const int rowL = tid >> 2, cL = tid & 3;

    if (tid < 128) Ps[tid] = pher[bN + m0 + tid];

    const ushortT *P0_ = Qa, *P1_ = Qb2, *P2_ = Qc, *P3_ = Ka, *P4_ = Kb2, *P5_ = Kc;
    const size_t oA_  = (bN + n0 + rowL) * (size_t)D_ + cL * 8;
    const size_t oAc_ = oA_;
    const size_t oB_  = (bN + m0 + rowL) * (size_t)D_ + cL * 8;
    const int ldst = rowL * TROW + cL * 8;

    f32x4 acc[4][2];
#pragma unroll
    for (int mi = 0; mi < 4; ++mi) { acc[mi][0] = (f32x4){0,0,0,0}; acc[mi][1] = (f32x4){0,0,0,0}; }

    int4 s[6];
    S6_LOAD(0)
    S6_STORE(0)
    S6_LOAD(32)

    for (int ks = 0; ks < 32; ++ks) {
        __syncthreads();
        if (ks < 31) S6_STORE((ks + 1) & 1)
        if (ks < 30) S6_LOAD((ks + 2) * 32)
        const ushortT* Tb = &T6[ks & 1][0];
        SPLIT6_COMPUTE(Tb, wr, wc, lane, acc)
    }

    // ---- fold to per-row top-8: 4 passes of 32 rows (R7-proven) ----
    const int r4 = (lane >> 4) * 4, cl = lane & 15;
    for (int p = 0; p < 4; ++p) {
        __syncthreads();                   // prior consumers of MV/T6 done
        if (wr == (p >> 1)) {
#pragma unroll
            for (int mi2 = 0; mi2 < 2; ++mi2) {
                const int mi = (p & 1) * 2 + mi2;
#pragma unroll
                for (int ni = 0; ni < 2; ++ni) {
                    int col = wc * 32 + ni * 16 + cl;
                    int m = m0 + col;
#pragma unroll
                    for (int r = 0; r < 4; ++r) {
                        int rloc = mi2 * 16 + r4 + r;
                        int n = n0 + p * 32 + rloc;
                        bool ok = (m <= n);
                        MV[rloc * 128 + col] = ok ? (acc[mi][ni][r] * SCALE_ + ALPHA_ * Ps[col])
                                                  : -INFINITY;
                        MI[rloc * 128 + col] = ok ? m : 0x7fffffff;
                    }
                }
            }
        }
        __syncthreads();
        if (tid < 128) {                   // partial top-8 over a 32-col quarter
            const int row = tid >> 2, q4 = tid & 3;
            float tv[KTOP]; int ti[KTOP];
#pragma unroll
            for (int j = 0; j < KTOP; ++j) { tv[j] = -INFINITY; ti[j] = 0x7fffffff; }
            for (int j = 0; j < 32; ++j) {
                float s2 = MV[row * 128 + q4 * 32 + j];
                if (s2 == -INFINITY) continue;
                topk_insert(tv, ti, s2, MI[row * 128 + q4 * 32 + j]);
            }
#pragma unroll
            for (int j = 0; j < KTOP; ++j) {
                PV[(row * 4 + q4) * 8 + j] = tv[j];
                PI[(row * 4 + q4) * 8 + j] = ti[j];
            }
        }
        __syncthreads();
        if (tid < 32) {                    // merge 4 partials -> chunk top-8
            float tv[KTOP]; int ti[KTOP];
#pragma unroll
            for (int j = 0; j < KTOP; ++j) { tv[j] = -INFINITY; ti[j] = 0x7fffffff; }
            for (int i = 0; i < 32; ++i) {
                float s2 = PV[tid * 32 + i];
                if (s2 == -INFINITY) continue;
                topk_insert(tv, ti, s2, PI[tid * 32 + i]);
            }
            int n = n0 + p * 32 + tid;
            size_t base = ((bN + n) * NCH + ch) * 8;
#pragma unroll
            for (int j = 0; j < KTOP; ++j) { WV[base + j] = tv[j]; WI[base + j] = ti[j]; }
        }
    }
}

// ---------------------------------------------------------------------------
// attn_merge: merge <=16 chunk lists -> top-8 -> softmax -> gather bf16 V ->
// CCb right half. Grid 2048 blocks, 4 rows each.
// ---------------------------------------------------------------------------
__global__ __launch_bounds__(256)
void attn_merge(const float* __restrict__ WV, const int* __restrict__ WI,
                const ushortT* __restrict__ V, ushortT* __restrict__ CCb)
{
    __shared__ float CV[4][128];
    __shared__ int   CI[4][128];
    __shared__ float Pp[4][KTOP];
    __shared__ int   Pi[4][KTOP];

    const int tid  = threadIdx.x;
    const int wv   = tid >> 6;
    const int lane = tid & 63;
    const int rid  = blockIdx.x * 4 + wv;
    const int b    = rid >> 11;
    const int n    = rid & (N_ - 1);
    const int ncand = ((n >> 7) + 1) * 8;
    const size_t cbase = (size_t)rid * (NCH * 8);

#pragma unroll
    for (int t = 0; t < 2; ++t) {
        int i = lane + t * 64;
        if (i < ncand) { CV[wv][i] = WV[cbase + i]; CI[wv][i] = WI[cbase + i]; }
        else           { CV[wv][i] = -INFINITY;     CI[wv][i] = 0x7fffffff;   }
    }
    __syncthreads();

    if (lane == 0) {
        float tv[KTOP]; int ti[KTOP];
#pragma unroll
        for (int j = 0; j < KTOP; ++j) { tv[j] = -INFINITY; ti[j] = 0x7fffffff; }
        for (int i = 0; i < 128; ++i) {
            float s = CV[wv][i];
            if (s == -INFINITY) continue;
            topk_insert(tv, ti, s, CI[wv][i]);
        }
        float mx = tv[0];
        float e[KTOP]; float sum = 0.f;
#pragma unroll
        for (int j = 0; j < KTOP; ++j) {
            e[j] = (tv[j] == -INFINITY) ? 0.f : __expf(tv[j] - mx);
            sum += e[j];
        }
        float inv = 1.f / sum;
#pragma unroll
        for (int j = 0; j < KTOP; ++j) {
            Pp[wv][j] = e[j] * inv;
            Pi[wv][j] = (tv[j] == -INFINITY) ? 0 : ti[j];
        }
    }
    __syncthreads();

    const size_t vbase = (size_t)b * N_ * D_;
#pragma unroll
    for (int it = 0; it < 2; ++it) {
        int c8 = (it * 64 + lane) * 8;
        float o[8];
#pragma unroll
        for (int u = 0; u < 8; ++u) o[u] = 0.f;
#pragma unroll
        for (int j = 0; j < KTOP; ++j) {
            float p = Pp[wv][j];
            ushort4 v0 = *reinterpret_cast<const ushort4*>(
                &V[vbase + (size_t)Pi[wv][j] * D_ + c8]);
            ushort4 v1 = *reinterpret_cast<const ushort4*>(
                &V[vbase + (size_t)Pi[wv][j] * D_ + c8 + 4]);
            o[0] = fmaf(p, b2f(v0.x), o[0]); o[1] = fmaf(p, b2f(v0.y), o[1]);
            o[2] = fmaf(p, b2f(v0.z), o[2]); o[3] = fmaf(p, b2f(v0.w), o[3]);
            o[4] = fmaf(p, b2f(v1.x), o[4]); o[5] = fmaf(p, b2f(v1.y), o[5]);
            o[6] = fmaf(p, b2f(v1.z), o[6]); o[7] = fmaf(p, b2f(v1.w), o[7]);
        }
        ushort4 ob0 = {f2b(o[0]), f2b(o[1]), f2b(o[2]), f2b(o[3])};
        ushort4 ob1 = {f2b(o[4]), f2b(o[5]), f2b(o[6]), f2b(o[7])};
        *reinterpret_cast<ushort4*>(&CCb[(size_t)rid * 2048 + 1024 + c8]) = ob0;
        *reinterpret_cast<ushort4*>(&CCb[(size_t)rid * 2048 + 1024 + c8 + 4]) = ob1;
    }
}

// ---------------------------------------------------------------------------
extern "C" void kernel_launch(void* const* d_in, const int* in_sizes, int n_in,
                              void* d_out, int out_size, void* d_ws, size_t ws_size,
                              hipStream_t stream)
{
    const float* mu   = (const float*)d_in[0];
    const float* pher = (const float*)d_in[1];
    const float* Wq   = (const float*)d_in[2];
    const float* bq   = (const float*)d_in[3];
    const float* Wk   = (const float*)d_in[4];
    const float* bk   = (const float*)d_in[5];
    const float* Wv   = (const float*)d_in[6];
    const float* bv   = (const float*)d_in[7];
    const float* Wm1  = (const float*)d_in[8];
    const float* bm1  = (const float*)d_in[9];
    const float* Wm2  = (const float*)d_in[10];
    const float* bm2  = (const float*)d_in[11];
    const float* Wo   = (const float*)d_in[12];
    const float* bo   = (const float*)d_in[13];
    float* out = (float*)d_out;
    float* ws  = (float*)d_ws;

    const size_t SZ  = (size_t)B_ * N_ * D_;    // 8388608 floats
    const size_t MEG = 1024 * 1024;             // floats
    const int M = B_ * N_;                      // 8192

    // ---- workspace map (float units), total 5.5*SZ + 3*MEG ≈ 197 MB ----
    ushortT* CCb   = (ushortT*)ws;                        // [8192][2048] bf16
    ushortT* mu_cp = CCb + 1024;                          // strided plane (CCb right half)
    float*   AbF   = ws + SZ;                             // f32 pre-act (phase 1)
    ushortT* Qa    = (ushortT*)(ws + SZ);                 // overlay after silu
    ushortT* Qb2   = Qa + SZ;
    float*   NbF   = ws + 2 * SZ;
    ushortT* Ka    = (ushortT*)(ws + 2 * SZ);
    ushortT* Kb2   = Ka + SZ;
    ushortT* mu_a  = (ushortT*)(ws + 3 * SZ);             // SZ ushorts
    ushortT* mu_bp = (ushortT*)(ws + 3 * SZ + SZ / 2);    // SZ ushorts
    float*   WVb   = (float*)(ws + 3 * SZ + SZ / 2);      // overlay after projections
    int*     WIb   = (int*)(WVb + MEG);
    ushortT* U     = (ushortT*)(ws + 4 * SZ);             // weights region, 3*MEG floats
    ushortT* Wt_m1 = U;                                   // [1024][2048]
    ushortT* Wt_m2 = U + 2 * MEG;                         // [1024][1024]
    ushortT* Wt_v  = U + 3 * MEG;                         // [1024][1024]
    ushortT* WqT_a = U;            ushortT* WqT_b = U + MEG;     ushortT* WqT_c = U + 2 * MEG;
    ushortT* WkT_a = U + 3 * MEG;  ushortT* WkT_b = U + 4 * MEG; ushortT* WkT_c = U + 5 * MEG;
    ushortT* Wt_o  = U;                                   // [1024][2048], after Q proj
    ushortT* Vb16  = (ushortT*)(ws + 4 * SZ + 3 * MEG);   // SZ ushorts
    ushortT* SbB   = (ushortT*)(ws + 4 * SZ + 3 * MEG + SZ / 2);  // SZ ushorts (then Qc)
    ushortT* Qc    = SbB;
    ushortT* Kc    = (ushortT*)(ws + 4 * SZ + 3 * MEG + SZ);      // SZ ushorts

    dim3 blk256(256), blk512(512);
    dim3 gD(8, 64);

    // 1. mu -> 3 bf16 planes (c strided into CCb right half)
    hipLaunchKernelGGL(split3_mu, dim3(SZ / 4 / 256), blk256, 0, stream, mu, mu_a, mu_bp, CCb);
    // 2. weight transposes (phase A)
    hipLaunchKernelGGL(transpose_f2b, dim3(64, 32), blk256, 0, stream, Wm1, Wt_m1, 2048, 1024);
    hipLaunchKernelGGL(transpose_f2b, dim3(32, 32), blk256, 0, stream, Wm2, Wt_m2, 1024, 1024);
    hipLaunchKernelGGL(transpose_f2b, dim3(32, 32), blk256, 0, stream, Wv, Wt_v, 1024, 1024);
    // 3-4. local pre-acts
    hipLaunchKernelGGL((mfma_gemm<0>), gD, blk256, 0, stream,
                       mu_a, D_, Wt_m1, 2048, bm1, (void*)AbF, D_, D_);
    hipLaunchKernelGGL((mfma_gemm<0>), gD, blk256, 0, stream,
                       mu_a, D_, Wt_m1 + 1024, 2048, (const float*)nullptr, (void*)NbF, D_, D_);
    // 5. silu-mean -> Sb (bf16)
    hipLaunchKernelGGL(silu_mean, dim3(SZ / 4 / 256), blk256, 0, stream, AbF, NbF, SbB);
    // 6. local msgs -> CCb left half
    hipLaunchKernelGGL((mfma_gemm<1>), gD, blk256, 0, stream,
                       SbB, D_, Wt_m2, D_, bm2, (void*)CCb, 2 * D_, D_);
    // 7. V -> bf16
    hipLaunchKernelGGL((mfma_gemm<1>), gD, blk256, 0, stream,
                       mu_a, D_, Wt_v, D_, bv, (void*)Vb16, D_, D_);
    // 8. Wq/Wk -> transposed split planes (phase B overlay)
    hipLaunchKernelGGL(transpose_split3, dim3(32, 32), blk256, 0, stream,
                       Wq, WqT_a, WqT_b, WqT_c, 1024, 1024);
    hipLaunchKernelGGL(transpose_split3, dim3(32, 32), blk256, 0, stream,
                       Wk, WkT_a, WkT_b, WkT_c, 1024, 1024);
    // 9-10. Q/K projections (split-MFMA, f32-equivalent) -> split planes
    hipLaunchKernelGGL(gemm_split6, gD, blk512, 0, stream,
                       mu_a, mu_bp, mu_cp, D_, 2 * D_,
                       WqT_a, WqT_b, WqT_c, bq, Qa, Qb2, Qc);
    hipLaunchKernelGGL(gemm_split6, gD, blk512, 0, stream,
                       mu_a, mu_bp, mu_cp, D_, 2 * D_,
                       WkT_a, WkT_b, WkT_c, bk, Ka, Kb2, Kc);
    // 11. Wo transpose (overlays dead WqT_a/b)
    hipLaunchKernelGGL(transpose_f2b, dim3(64, 32), blk256, 0, stream, Wo, Wt_o, 2048, 1024);
    // 12. scores + per-chunk top-8
    hipLaunchKernelGGL(attn_scores_mfma2, dim3(136, B_), blk512, 0, stream,
                       Qa, Qb2, Qc, Ka, Kb2, Kc, pher, WVb, WIb);
    // 13. merge + softmax + V gather -> CCb right half
    hipLaunchKernelGGL(attn_merge, dim3(M / 4), blk256, 0, stream, WVb, WIb, Vb16, CCb);
    // 14. out = CCb @ Wo + bo
    hipLaunchKernelGGL((mfma_gemm<0>), gD, blk256, 0, stream,
                       CCb, 2 * D_, Wt_o, 2048, bo, (void*)out, D_, 2 * D_);

    (void)in_sizes; (void)n_in; (void)out_size; (void)ws_size;
}

// Round 10
// 939.277 us; speedup vs baseline: 2.2247x; 2.2247x over previous
//
#include <hip/hip_runtime.h>
#include <hip/hip_bf16.h>
#include <math.h>

#define B_ 4
#define N_ 2048
#define D_ 1024
#define WIN_ 4
#define KTOP 8
#define ALPHA_ 0.3f
#define SCALE_ (1.0f/32.0f)
#define NCH 16          // N_/128 col chunks
#define TROW 34         // ushorts per LDS tile row (68B stride; 52.7KB -> 3 blocks/CU)
#define TPLANE (128 * TROW)

typedef unsigned short ushortT;
typedef __attribute__((ext_vector_type(8))) short short8v;   // 8 bf16 (4 VGPR)
typedef __attribute__((ext_vector_type(4))) float f32x4;

__device__ inline ushortT f2b(float f) {     // f32 -> bf16 RNE
    unsigned int u = __float_as_uint(f);
    unsigned int r = (u + 0x7fffu + ((u >> 16) & 1u)) >> 16;
    return (ushortT)r;
}
__device__ inline float b2f(ushortT u) {
    return __uint_as_float(((unsigned int)u) << 16);
}

// ---------------------------------------------------------------------------
// mu f32 -> 3 bf16 planes: a contiguous, b contiguous, c STRIDED into CCb's
// right half (row*2048 + 1024 + col).
// ---------------------------------------------------------------------------
__global__ __launch_bounds__(256)
void split3_mu(const float* __restrict__ src, ushortT* __restrict__ Pa,
               ushortT* __restrict__ Pb, ushortT* __restrict__ CCbase)
{
    size_t base = ((size_t)blockIdx.x * 256 + threadIdx.x) * 4;
    int row = (int)(base >> 10);
    int col = (int)(base & 1023);
    float4 v = *reinterpret_cast<const float4*>(&src[base]);
    ushort4 pa, pb, pc;
    float vv[4] = {v.x, v.y, v.z, v.w};
#pragma unroll
    for (int j = 0; j < 4; ++j) {
        float f = vv[j];
        ushortT a = f2b(f);  float r1 = f - b2f(a);
        ushortT b = f2b(r1); float r2 = r1 - b2f(b);
        ushortT c = f2b(r2);
        ((ushortT*)&pa)[j] = a; ((ushortT*)&pb)[j] = b; ((ushortT*)&pc)[j] = c;
    }
    *reinterpret_cast<ushort4*>(&Pa[base]) = pa;
    *reinterpret_cast<ushort4*>(&Pb[base]) = pb;
    *reinterpret_cast<ushort4*>(&CCbase[(size_t)row * 2048 + 1024 + col]) = pc;
}

// ---------------------------------------------------------------------------
// W [K][Nn] f32 -> Wt [Nn][K] bf16 (single plane)
// ---------------------------------------------------------------------------
__global__ __launch_bounds__(256)
void transpose_f2b(const float* __restrict__ W, ushortT* __restrict__ Wt,
                   int K, int Nn)
{
    __shared__ float t[32][33];
    const int k0 = blockIdx.x * 32, n0 = blockIdx.y * 32;
    const int tx = threadIdx.x & 31, ty8 = threadIdx.x >> 5;
#pragma unroll
    for (int p = 0; p < 4; ++p) {
        int kk = p * 8 + ty8;
        t[kk][tx] = W[(size_t)(k0 + kk) * Nn + n0 + tx];
    }
    __syncthreads();
#pragma unroll
    for (int p = 0; p < 4; ++p) {
        int nn = p * 8 + ty8;
        Wt[(size_t)(n0 + nn) * K + k0 + tx] = f2b(t[tx][nn]);
    }
}

// ---------------------------------------------------------------------------
// W [K][Nn] f32 -> 3 transposed bf16 planes [Nn][K]
// ---------------------------------------------------------------------------
__global__ __launch_bounds__(256)
void transpose_split3(const float* __restrict__ W, ushortT* __restrict__ Pa,
                      ushortT* __restrict__ Pb, ushortT* __restrict__ Pc,
                      int K, int Nn)
{
    __shared__ float t[32][33];
    const int k0 = blockIdx.x * 32, n0 = blockIdx.y * 32;
    const int tx = threadIdx.x & 31, ty8 = threadIdx.x >> 5;
#pragma unroll
    for (int p = 0; p < 4; ++p) {
        int kk = p * 8 + ty8;
        t[kk][tx] = W[(size_t)(k0 + kk) * Nn + n0 + tx];
    }
    __syncthreads();
#pragma unroll
    for (int p = 0; p < 4; ++p) {
        int nn = p * 8 + ty8;
        float f = t[tx][nn];
        ushortT a = f2b(f);  float r1 = f - b2f(a);
        ushortT b = f2b(r1); float r2 = r1 - b2f(b);
        ushortT c = f2b(r2);
        size_t o = (size_t)(n0 + nn) * K + k0 + tx;
        Pa[o] = a; Pb[o] = b; Pc[o] = c;
    }
}

// ---------------------------------------------------------------------------
// bf16 MFMA GEMM (proven): 128x128 tile, BK=64, 4 waves, 64x64/wave.
// ---------------------------------------------------------------------------
template<int BF16OUT>
__global__ __launch_bounds__(256)
void mfma_gemm(const ushortT* __restrict__ A, int lda,
               const ushortT* __restrict__ Bt, int ldb,
               const float* __restrict__ bias,
               void* __restrict__ Cout, int ldc, int K)
{
    __shared__ ushortT AsL[128 * 72];
    __shared__ ushortT BsL[128 * 72];
    const int tid = threadIdx.x;
    const int m0 = blockIdx.y * 128;
    const int n0 = blockIdx.x * 128;
    const int w = tid >> 6, lane = tid & 63;
    const int wr = w >> 1, wc = w & 1;

    f32x4 acc[4][4];
#pragma unroll
    for (int mi = 0; mi < 4; ++mi)
#pragma unroll
        for (int ni = 0; ni < 4; ++ni) acc[mi][ni] = (f32x4){0.f, 0.f, 0.f, 0.f};

    for (int k0 = 0; k0 < K; k0 += 64) {
#pragma unroll
        for (int it = 0; it < 4; ++it) {
            int idx = tid + it * 256;        // 0..1023
            int row = idx >> 3, c = idx & 7;
            int4 va = *reinterpret_cast<const int4*>(&A[(size_t)(m0 + row) * lda + k0 + c * 8]);
            *reinterpret_cast<int4*>(&AsL[row * 72 + c * 8]) = va;
            int4 vb = *reinterpret_cast<const int4*>(&Bt[(size_t)(n0 + row) * ldb + k0 + c * 8]);
            *reinterpret_cast<int4*>(&BsL[row * 72 + c * 8]) = vb;
        }
        __syncthreads();
#pragma unroll
        for (int kh = 0; kh < 2; ++kh) {
            const int ko = kh * 32 + (lane >> 4) * 8;
            const int rr = lane & 15;
            short8v af[4], bf[4];
#pragma unroll
            for (int mi = 0; mi < 4; ++mi)
                af[mi] = *reinterpret_cast<const short8v*>(&AsL[(wr * 64 + mi * 16 + rr) * 72 + ko]);
#pragma unroll
            for (int ni = 0; ni < 4; ++ni)
                bf[ni] = *reinterpret_cast<const short8v*>(&BsL[(wc * 64 + ni * 16 + rr) * 72 + ko]);
#pragma unroll
            for (int mi = 0; mi < 4; ++mi)
#pragma unroll
                for (int ni = 0; ni < 4; ++ni)
                    acc[mi][ni] = __builtin_amdgcn_mfma_f32_16x16x32_bf16(
                        af[mi], bf[ni], acc[mi][ni], 0, 0, 0);
        }
        __syncthreads();
    }

    const int r4 = (lane >> 4) * 4, cl = lane & 15;
#pragma unroll
    for (int mi = 0; mi < 4; ++mi)
#pragma unroll
        for (int ni = 0; ni < 4; ++ni) {
            int row = m0 + wr * 64 + mi * 16 + r4;
            int col = n0 + wc * 64 + ni * 16 + cl;
            float bb = bias ? bias[col] : 0.f;
#pragma unroll
            for (int r = 0; r < 4; ++r) {
                float v = acc[mi][ni][r] + bb;
                if (BF16OUT)
                    ((ushortT*)Cout)[(size_t)(row + r) * ldc + col] = f2b(v);
                else
                    ((float*)Cout)[(size_t)(row + r) * ldc + col] = v;
            }
        }
}

// ---------------------------------------------------------------------------
// S[b,n,:] = mean_w silu(A + Nb shifted), output bf16.
// ---------------------------------------------------------------------------
__global__ __launch_bounds__(256)
void silu_mean(const float* __restrict__ A, const float* __restrict__ Nb,
               ushortT* __restrict__ Sb)
{
    size_t idx4 = (size_t)blockIdx.x * blockDim.x + threadIdx.x;
    size_t base = idx4 << 2;
    int n = (int)((base >> 10) & (N_ - 1));
    float4 a = *reinterpret_cast<const float4*>(&A[base]);
    float sx = 0.f, sy = 0.f, sz = 0.f, sw = 0.f;
#pragma unroll
    for (int w = 1; w <= WIN_; ++w) {
        float xx = a.x, xy = a.y, xz = a.z, xw = a.w;
        if (n >= w) {
            const float4 nb = *reinterpret_cast<const float4*>(&Nb[base - (size_t)w * D_]);
            xx += nb.x; xy += nb.y; xz += nb.z; xw += nb.w;
        }
        sx += xx / (1.f + __expf(-xx));
        sy += xy / (1.f + __expf(-xy));
        sz += xz / (1.f + __expf(-xz));
        sw += xw / (1.f + __expf(-xw));
    }
    ushort4 o = {f2b(sx * 0.25f), f2b(sy * 0.25f), f2b(sz * 0.25f), f2b(sw * 0.25f)};
    *reinterpret_cast<ushort4*>(&Sb[base]) = o;
}

// ---------------------------------------------------------------------------
__device__ inline void topk_insert(float (&tv)[KTOP], int (&ti)[KTOP], float s, int m)
{
    if ((s > tv[KTOP-1]) || (s == tv[KTOP-1] && m < ti[KTOP-1])) {
        float cs = s; int ci = m;
#pragma unroll
        for (int q = 0; q < KTOP; ++q) {
            bool beats = (cs > tv[q]) || (cs == tv[q] && ci < ti[q]);
            if (beats) { float t0 = tv[q]; int t1 = ti[q];
                         tv[q] = cs; ti[q] = ci; cs = t0; ci = t1; }
        }
    }
}

// ---------------------------------------------------------------------------
// 6-product split-MFMA core (R7-proven): 8 waves, wave tile 64x32
// (wr in {0,1}, wc in {0..3}), acc[4][2]. Products p+q<=2 (ah,al,am,bh,bl,ch).
// ---------------------------------------------------------------------------
#define SPLIT6_COMPUTE(T6, wr, wc, lane, acc)                                   \
    {                                                                           \
        const int rr_ = (lane) & 15, ko_ = ((lane) >> 4) * 8;                   \
        _Pragma("unroll")                                                       \
        for (int p_ = 0; p_ < 3; ++p_) {                                        \
            short8v aF_[4];                                                     \
            _Pragma("unroll")                                                   \
            for (int mi_ = 0; mi_ < 4; ++mi_)                                   \
                aF_[mi_] = *reinterpret_cast<const short8v*>(                   \
                    &T6[p_ * TPLANE + ((wr) * 64 + mi_ * 16 + rr_) * TROW + ko_]);\
            _Pragma("unroll")                                                   \
            for (int q_ = 0; q_ < 3; ++q_) {                                    \
                if (p_ + q_ > 2) continue;                                      \
                short8v b0_ = *reinterpret_cast<const short8v*>(                \
                    &T6[(3 + q_) * TPLANE + ((wc) * 32 + rr_) * TROW + ko_]);   \
                short8v b1_ = *reinterpret_cast<const short8v*>(                \
                    &T6[(3 + q_) * TPLANE + ((wc) * 32 + 16 + rr_) * TROW + ko_]);\
                _Pragma("unroll")                                               \
                for (int mi_ = 0; mi_ < 4; ++mi_) {                             \
                    acc[mi_][0] = __builtin_amdgcn_mfma_f32_16x16x32_bf16(      \
                        aF_[mi_], b0_, acc[mi_][0], 0, 0, 0);                   \
                    acc[mi_][1] = __builtin_amdgcn_mfma_f32_16x16x32_bf16(      \
                        aF_[mi_], b1_, acc[mi_][1], 0, 0, 0);                   \
                }                                                               \
            }                                                                   \
        }                                                                       \
    }

// ---------------------------------------------------------------------------
// gemm_split6: out = (A0+A1+A2) @ (B0+B1+B2)^T + bias, 6 kept products,
// f32-equivalent. 512 thr, 8 waves, BK=32, reg-prefetch, XCD swizzle.
// Output split into 3 bf16 planes. (R7-proven structure, TROW=34.)
// ---------------------------------------------------------------------------
__global__ __launch_bounds__(512, 4)
void gemm_split6(const ushortT* __restrict__ A0, const ushortT* __restrict__ A1,
                 const ushortT* __restrict__ A2, int lda, int ldac,
                 const ushortT* __restrict__ B0, const ushortT* __restrict__ B1,
                 const ushortT* __restrict__ B2,
                 const float* __restrict__ bias,
                 ushortT* __restrict__ Pa, ushortT* __restrict__ Pb,
                 ushortT* __restrict__ Pc)
{
    __shared__ ushortT T6[6 * TPLANE];     // 52224 B -> 3 blocks/CU

    int lin = blockIdx.y * 8 + blockIdx.x;                // 0..511
    lin = (lin & 7) * 64 + (lin >> 3);                    // XCD-chunked
    const int m0 = (lin >> 3) * 128;
    const int n0 = (lin & 7) * 128;

    const int tid = threadIdx.x;
    const int wid = tid >> 6, lane = tid & 63;
    const int wr = wid >> 2, wc = wid & 3;
    const int rowL = tid >> 2, cL = tid & 3;              // stage: row 0..127, 16B chunk

    const size_t offA  = (size_t)(m0 + rowL) * lda + cL * 8;
    const size_t offAc = (size_t)(m0 + rowL) * ldac + cL * 8;
    const size_t offB  = (size_t)(n0 + rowL) * D_ + cL * 8;
    const int ldst = rowL * TROW + cL * 8;                // ushort offset in tile

    f32x4 acc[4][2];
#pragma unroll
    for (int mi = 0; mi < 4; ++mi) { acc[mi][0] = (f32x4){0,0,0,0}; acc[mi][1] = (f32x4){0,0,0,0}; }

    int4 s0, s1, s2, s3, s4, s5;
    s0 = *reinterpret_cast<const int4*>(&A0[offA]);
    s1 = *reinterpret_cast<const int4*>(&A1[offA]);
    s2 = *reinterpret_cast<const int4*>(&A2[offAc]);
    s3 = *reinterpret_cast<const int4*>(&B0[offB]);
    s4 = *reinterpret_cast<const int4*>(&B1[offB]);
    s5 = *reinterpret_cast<const int4*>(&B2[offB]);

    for (int ks = 0; ks < 32; ++ks) {
        __syncthreads();
        *reinterpret_cast<int4*>(&T6[0 * TPLANE + ldst]) = s0;
        *reinterpret_cast<int4*>(&T6[1 * TPLANE + ldst]) = s1;
        *reinterpret_cast<int4*>(&T6[2 * TPLANE + ldst]) = s2;
        *reinterpret_cast<int4*>(&T6[3 * TPLANE + ldst]) = s3;
        *reinterpret_cast<int4*>(&T6[4 * TPLANE + ldst]) = s4;
        *reinterpret_cast<int4*>(&T6[5 * TPLANE + ldst]) = s5;
        __syncthreads();
        if (ks < 31) {
            const int kk = (ks + 1) * 32;
            s0 = *reinterpret_cast<const int4*>(&A0[offA + kk]);
            s1 = *reinterpret_cast<const int4*>(&A1[offA + kk]);
            s2 = *reinterpret_cast<const int4*>(&A2[offAc + kk]);
            s3 = *reinterpret_cast<const int4*>(&B0[offB + kk]);
            s4 = *reinterpret_cast<const int4*>(&B1[offB + kk]);
            s5 = *reinterpret_cast<const int4*>(&B2[offB + kk]);
        }
        SPLIT6_COMPUTE(T6, wr, wc, lane, acc)
    }

    const int r4 = (lane >> 4) * 4, cl = lane & 15;
#pragma unroll
    for (int mi = 0; mi < 4; ++mi)
#pragma unroll
        for (int ni = 0; ni < 2; ++ni) {
            int col = n0 + wc * 32 + ni * 16 + cl;
            float bb = bias[col];
#pragma unroll
            for (int r = 0; r < 4; ++r) {
                int row = m0 + wr * 64 + mi * 16 + r4 + r;
                float v = acc[mi][ni][r] + bb;
                ushortT a = f2b(v);  float r1 = v - b2f(a);
                ushortT b = f2b(r1); float r2 = r1 - b2f(b);
                ushortT c = f2b(r2);
                size_t o = (size_t)row * D_ + col;
                Pa[o] = a; Pb[o] = b; Pc[o] = c;
            }
        }
}

// ---------------------------------------------------------------------------
// attn_scores_mfma2: 6-product split scores + mask + pheromone + per-chunk
// top-8. 512 thr, 8 waves, BK=32, reg-prefetch, XCD swizzle. (R7, TROW=34.)
// ---------------------------------------------------------------------------
__global__ __launch_bounds__(512, 4)
void attn_scores_mfma2(const ushortT* __restrict__ Qa, const ushortT* __restrict__ Qb2,
                       const ushortT* __restrict__ Qc,
                       const ushortT* __restrict__ Ka, const ushortT* __restrict__ Kb2,
                       const ushortT* __restrict__ Kc,
                       const float* __restrict__ pher,
                       float* __restrict__ WV, int* __restrict__ WI)
{
    __shared__ ushortT T6[6 * TPLANE];     // 52224 B
    __shared__ float Ps[128];
    float* MV = reinterpret_cast<float*>(&T6[0]);                    // [32][128]
    int*   MI = reinterpret_cast<int*>((char*)&T6[0] + 16384);       // [32][128]
    float* PV = reinterpret_cast<float*>((char*)&T6[0] + 32768);     // [32][4][8]
    int*   PI = reinterpret_cast<int*>((char*)&T6[0] + 36864);       // [32][4][8]

    int lin = blockIdx.y * 136 + blockIdx.x;              // 0..543
    lin = (lin & 7) * 68 + (lin >> 3);                    // XCD-chunked, 544=8*68
    const int b = lin / 136;
    const int xy = lin - b * 136;
    int g = 0;
    while ((g + 1) * (g + 2) / 2 <= xy) ++g;
    const int ch = xy - g * (g + 1) / 2;
    const int n0 = g * 128;
    const int m0 = ch * 128;
    const size_t bN = (size_t)b * N_;

    const int tid = threadIdx.x;
    const int wid = tid >> 6, lane = tid & 63;
    const int wr = wid >> 2, wc = wid & 3;
    const int rowL = tid >> 2, cL = tid & 3;

    if (tid < 128) Ps[tid] = pher[bN + m0 + tid];

    const size_t offQ = (bN + n0 + rowL) * (size_t)D_ + cL * 8;
    const size_t offK = (bN + m0 + rowL) * (size_t)D_ + cL * 8;
    const int ldst = rowL * TROW + cL * 8;

    f32x4 acc[4][2];
#pragma unroll
    for (int mi = 0; mi < 4; ++mi) { acc[mi][0] = (f32x4){0,0,0,0}; acc[mi][1] = (f32x4){0,0,0,0}; }

    int4 s0, s1, s2, s3, s4, s5;
    s0 = *reinterpret_cast<const int4*>(&Qa[offQ]);
    s1 = *reinterpret_cast<const int4*>(&Qb2[offQ]);
    s2 = *reinterpret_cast<const int4*>(&Qc[offQ]);
    s3 = *reinterpret_cast<const int4*>(&Ka[offK]);
    s4 = *reinterpret_cast<const int4*>(&Kb2[offK]);
    s5 = *reinterpret_cast<const int4*>(&Kc[offK]);

    for (int ks = 0; ks < 32; ++ks) {
        __syncthreads();
        *reinterpret_cast<int4*>(&T6[0 * TPLANE + ldst]) = s0;
        *reinterpret_cast<int4*>(&T6[1 * TPLANE + ldst]) = s1;
        *reinterpret_cast<int4*>(&T6[2 * TPLANE + ldst]) = s2;
        *reinterpret_cast<int4*>(&T6[3 * TPLANE + ldst]) = s3;
        *reinterpret_cast<int4*>(&T6[4 * TPLANE + ldst]) = s4;
        *reinterpret_cast<int4*>(&T6[5 * TPLANE + ldst]) = s5;
        __syncthreads();
        if (ks < 31) {
            const int kk = (ks + 1) * 32;
            s0 = *reinterpret_cast<const int4*>(&Qa[offQ + kk]);
            s1 = *reinterpret_cast<const int4*>(&Qb2[offQ + kk]);
            s2 = *reinterpret_cast<const int4*>(&Qc[offQ + kk]);
            s3 = *reinterpret_cast<const int4*>(&Ka[offK + kk]);
            s4 = *reinterpret_cast<const int4*>(&Kb2[offK + kk]);
            s5 = *reinterpret_cast<const int4*>(&Kc[offK + kk]);
        }
        SPLIT6_COMPUTE(T6, wr, wc, lane, acc)
    }

    // ---- fold to per-row top-8: 4 passes of 32 rows ----
    const int r4 = (lane >> 4) * 4, cl = lane & 15;
    for (int p = 0; p < 4; ++p) {
        __syncthreads();                       // T6/MV consumers done
        if (wr == (p >> 1)) {
#pragma unroll
            for (int mi2 = 0; mi2 < 2; ++mi2) {
                const int mi = (p & 1) * 2 + mi2;
#pragma unroll
                for (int ni = 0; ni < 2; ++ni) {
                    int col = wc * 32 + ni * 16 + cl;
                    int m = m0 + col;
#pragma unroll
                    for (int r = 0; r < 4; ++r) {
                        int rloc = mi2 * 16 + r4 + r;
                        int n = n0 + p * 32 + rloc;
                        bool ok = (m <= n);
                        MV[rloc * 128 + col] = ok ? (acc[mi][ni][r] * SCALE_ + ALPHA_ * Ps[col])
                                                  : -INFINITY;
                        MI[rloc * 128 + col] = ok ? m : 0x7fffffff;
                    }
                }
            }
        }
        __syncthreads();
        if (tid < 128) {                       // partial top-8 over a 32-col quarter
            const int row = tid >> 2, q4 = tid & 3;
            float tv[KTOP]; int ti[KTOP];
#pragma unroll
            for (int j = 0; j < KTOP; ++j) { tv[j] = -INFINITY; ti[j] = 0x7fffffff; }
            for (int j = 0; j < 32; ++j) {
                float s2 = MV[row * 128 + q4 * 32 + j];
                if (s2 == -INFINITY) continue;
                topk_insert(tv, ti, s2, MI[row * 128 + q4 * 32 + j]);
            }
#pragma unroll
            for (int j = 0; j < KTOP; ++j) {
                PV[(row * 4 + q4) * 8 + j] = tv[j];
                PI[(row * 4 + q4) * 8 + j] = ti[j];
            }
        }
        __syncthreads();
        if (tid < 32) {                        // merge 4 partials -> chunk top-8
            float tv[KTOP]; int ti[KTOP];
#pragma unroll
            for (int j = 0; j < KTOP; ++j) { tv[j] = -INFINITY; ti[j] = 0x7fffffff; }
            for (int i = 0; i < 32; ++i) {
                float s2 = PV[tid * 32 + i];
                if (s2 == -INFINITY) continue;
                topk_insert(tv, ti, s2, PI[tid * 32 + i]);
            }
            int n = n0 + p * 32 + tid;
            size_t base = ((bN + n) * NCH + ch) * 8;
#pragma unroll
            for (int j = 0; j < KTOP; ++j) { WV[base + j] = tv[j]; WI[base + j] = ti[j]; }
        }
    }
}

// ---------------------------------------------------------------------------
// attn_merge: merge <=16 chunk lists -> top-8 -> softmax -> gather bf16 V ->
// CCb right half. Grid 2048 blocks, 4 rows each.
// ---------------------------------------------------------------------------
__global__ __launch_bounds__(256)
void attn_merge(const float* __restrict__ WV, const int* __restrict__ WI,
                const ushortT* __restrict__ V, ushortT* __restrict__ CCb)
{
    __shared__ float CV[4][128];
    __shared__ int   CI[4][128];
    __shared__ float Pp[4][KTOP];
    __shared__ int   Pi[4][KTOP];

    const int tid  = threadIdx.x;
    const int wv   = tid >> 6;
    const int lane = tid & 63;
    const int rid  = blockIdx.x * 4 + wv;
    const int b    = rid >> 11;
    const int n    = rid & (N_ - 1);
    const int ncand = ((n >> 7) + 1) * 8;
    const size_t cbase = (size_t)rid * (NCH * 8);

#pragma unroll
    for (int t = 0; t < 2; ++t) {
        int i = lane + t * 64;
        if (i < ncand) { CV[wv][i] = WV[cbase + i]; CI[wv][i] = WI[cbase + i]; }
        else           { CV[wv][i] = -INFINITY;     CI[wv][i] = 0x7fffffff;   }
    }
    __syncthreads();

    if (lane == 0) {
        float tv[KTOP]; int ti[KTOP];
#pragma unroll
        for (int j = 0; j < KTOP; ++j) { tv[j] = -INFINITY; ti[j] = 0x7fffffff; }
        for (int i = 0; i < 128; ++i) {
            float s = CV[wv][i];
            if (s == -INFINITY) continue;
            topk_insert(tv, ti, s, CI[wv][i]);
        }
        float mx = tv[0];
        float e[KTOP]; float sum = 0.f;
#pragma unroll
        for (int j = 0; j < KTOP; ++j) {
            e[j] = (tv[j] == -INFINITY) ? 0.f : __expf(tv[j] - mx);
            sum += e[j];
        }
        float inv = 1.f / sum;
#pragma unroll
        for (int j = 0; j < KTOP; ++j) {
            Pp[wv][j] = e[j] * inv;
            Pi[wv][j] = (tv[j] == -INFINITY) ? 0 : ti[j];
        }
    }
    __syncthreads();

    const size_t vbase = (size_t)b * N_ * D_;
#pragma unroll
    for (int it = 0; it < 2; ++it) {
        int c8 = (it * 64 + lane) * 8;
        float o[8];
#pragma unroll
        for (int u = 0; u < 8; ++u) o[u] = 0.f;
#pragma unroll
        for (int j = 0; j < KTOP; ++j) {
            float p = Pp[wv][j];
            ushort4 v0 = *reinterpret_cast<const ushort4*>(
                &V[vbase + (size_t)Pi[wv][j] * D_ + c8]);
            ushort4 v1 = *reinterpret_cast<const ushort4*>(
                &V[vbase + (size_t)Pi[wv][j] * D_ + c8 + 4]);
            o[0] = fmaf(p, b2f(v0.x), o[0]); o[1] = fmaf(p, b2f(v0.y), o[1]);
            o[2] = fmaf(p, b2f(v0.z), o[2]); o[3] = fmaf(p, b2f(v0.w), o[3]);
            o[4] = fmaf(p, b2f(v1.x), o[4]); o[5] = fmaf(p, b2f(v1.y), o[5]);
            o[6] = fmaf(p, b2f(v1.z), o[6]); o[7] = fmaf(p, b2f(v1.w), o[7]);
        }
        ushort4 ob0 = {f2b(o[0]), f2b(o[1]), f2b(o[2]), f2b(o[3])};
        ushort4 ob1 = {f2b(o[4]), f2b(o[5]), f2b(o[6]), f2b(o[7])};
        *reinterpret_cast<ushort4*>(&CCb[(size_t)rid * 2048 + 1024 + c8]) = ob0;
        *reinterpret_cast<ushort4*>(&CCb[(size_t)rid * 2048 + 1024 + c8 + 4]) = ob1;
    }
}

// ---------------------------------------------------------------------------
extern "C" void kernel_launch(void* const* d_in, const int* in_sizes, int n_in,
                              void* d_out, int out_size, void* d_ws, size_t ws_size,
                              hipStream_t stream)
{
    const float* mu   = (const float*)d_in[0];
    const float* pher = (const float*)d_in[1];
    const float* Wq   = (const float*)d_in[2];
    const float* bq   = (const float*)d_in[3];
    const float* Wk   = (const float*)d_in[4];
    const float* bk   = (const float*)d_in[5];
    const float* Wv   = (const float*)d_in[6];
    const float* bv   = (const float*)d_in[7];
    const float* Wm1  = (const float*)d_in[8];
    const float* bm1  = (const float*)d_in[9];
    const float* Wm2  = (const float*)d_in[10];
    const float* bm2  = (const float*)d_in[11];
    const float* Wo   = (const float*)d_in[12];
    const float* bo   = (const float*)d_in[13];
    float* out = (float*)d_out;
    float* ws  = (float*)d_ws;

    const size_t SZ  = (size_t)B_ * N_ * D_;    // 8388608 floats
    const size_t MEG = 1024 * 1024;             // floats
    const int M = B_ * N_;                      // 8192

    // ---- workspace map (float units), total 5.5*SZ + 3*MEG ≈ 197 MB ----
    ushortT* CCb   = (ushortT*)ws;                        // [8192][2048] bf16
    ushortT* mu_cp = CCb + 1024;                          // strided plane (CCb right half)
    float*   AbF   = ws + SZ;                             // f32 pre-act (phase 1)
    ushortT* Qa    = (ushortT*)(ws + SZ);                 // overlay after silu
    ushortT* Qb2   = Qa + SZ;
    float*   NbF   = ws + 2 * SZ;
    ushortT* Ka    = (ushortT*)(ws + 2 * SZ);
    ushortT* Kb2   = Ka + SZ;
    ushortT* mu_a  = (ushortT*)(ws + 3 * SZ);             // SZ ushorts
    ushortT* mu_bp = (ushortT*)(ws + 3 * SZ + SZ / 2);    // SZ ushorts
    float*   WVb   = (float*)(ws + 3 * SZ + SZ / 2);      // overlay after projections
    int*     WIb   = (int*)(WVb + MEG);
    ushortT* U     = (ushortT*)(ws + 4 * SZ);             // weights region, 3*MEG floats
    ushortT* Wt_m1 = U;                                   // [1024][2048]
    ushortT* Wt_m2 = U + 2 * MEG;                         // [1024][1024]
    ushortT* Wt_v  = U + 3 * MEG;                         // [1024][1024]
    ushortT* WqT_a = U;            ushortT* WqT_b = U + MEG;     ushortT* WqT_c = U + 2 * MEG;
    ushortT* WkT_a = U + 3 * MEG;  ushortT* WkT_b = U + 4 * MEG; ushortT* WkT_c = U + 5 * MEG;
    ushortT* Wt_o  = U;                                   // [1024][2048], after Q proj
    ushortT* Vb16  = (ushortT*)(ws + 4 * SZ + 3 * MEG);   // SZ ushorts
    ushortT* SbB   = (ushortT*)(ws + 4 * SZ + 3 * MEG + SZ / 2);  // SZ ushorts (then Qc)
    ushortT* Qc    = SbB;
    ushortT* Kc    = (ushortT*)(ws + 4 * SZ + 3 * MEG + SZ);      // SZ ushorts

    dim3 blk256(256), blk512(512);
    dim3 gD(8, 64);

    // 1. mu -> 3 bf16 planes (c strided into CCb right half)
    hipLaunchKernelGGL(split3_mu, dim3(SZ / 4 / 256), blk256, 0, stream, mu, mu_a, mu_bp, CCb);
    // 2. weight transposes (phase A)
    hipLaunchKernelGGL(transpose_f2b, dim3(64, 32), blk256, 0, stream, Wm1, Wt_m1, 2048, 1024);
    hipLaunchKernelGGL(transpose_f2b, dim3(32, 32), blk256, 0, stream, Wm2, Wt_m2, 1024, 1024);
    hipLaunchKernelGGL(transpose_f2b, dim3(32, 32), blk256, 0, stream, Wv, Wt_v, 1024, 1024);
    // 3-4. local pre-acts
    hipLaunchKernelGGL((mfma_gemm<0>), gD, blk256, 0, stream,
                       mu_a, D_, Wt_m1, 2048, bm1, (void*)AbF, D_, D_);
    hipLaunchKernelGGL((mfma_gemm<0>), gD, blk256, 0, stream,
                       mu_a, D_, Wt_m1 + 1024, 2048, (const float*)nullptr, (void*)NbF, D_, D_);
    // 5. silu-mean -> Sb (bf16)
    hipLaunchKernelGGL(silu_mean, dim3(SZ / 4 / 256), blk256, 0, stream, AbF, NbF, SbB);
    // 6. local msgs -> CCb left half
    hipLaunchKernelGGL((mfma_gemm<1>), gD, blk256, 0, stream,
                       SbB, D_, Wt_m2, D_, bm2, (void*)CCb, 2 * D_, D_);
    // 7. V -> bf16
    hipLaunchKernelGGL((mfma_gemm<1>), gD, blk256, 0, stream,
                       mu_a, D_, Wt_v, D_, bv, (void*)Vb16, D_, D_);
    // 8. Wq/Wk -> transposed split planes (phase B overlay)
    hipLaunchKernelGGL(transpose_split3, dim3(32, 32), blk256, 0, stream,
                       Wq, WqT_a, WqT_b, WqT_c, 1024, 1024);
    hipLaunchKernelGGL(transpose_split3, dim3(32, 32), blk256, 0, stream,
                       Wk, WkT_a, WkT_b, WkT_c, 1024, 1024);
    // 9-10. Q/K projections (split-MFMA, f32-equivalent) -> split planes
    hipLaunchKernelGGL(gemm_split6, gD, blk512, 0, stream,
                       mu_a, mu_bp, mu_cp, D_, 2 * D_,
                       WqT_a, WqT_b, WqT_c, bq, Qa, Qb2, Qc);
    hipLaunchKernelGGL(gemm_split6, gD, blk512, 0, stream,
                       mu_a, mu_bp, mu_cp, D_, 2 * D_,
                       WkT_a, WkT_b, WkT_c, bk, Ka, Kb2, Kc);
    // 11. Wo transpose (overlays dead WqT_a/b)
    hipLaunchKernelGGL(transpose_f2b, dim3(64, 32), blk256, 0, stream, Wo, Wt_o, 2048, 1024);
    // 12. scores + per-chunk top-8
    hipLaunchKernelGGL(attn_scores_mfma2, dim3(136, B_), blk512, 0, stream,
                       Qa, Qb2, Qc, Ka, Kb2, Kc, pher, WVb, WIb);
    // 13. merge + softmax + V gather -> CCb right half
    hipLaunchKernelGGL(attn_merge, dim3(M / 4), blk256, 0, stream, WVb, WIb, Vb16, CCb);
    // 14. out = CCb @ Wo + bo
    hipLaunchKernelGGL((mfma_gemm<0>), gD, blk256, 0, stream,
                       CCb, 2 * D_, Wt_o, 2048, bo, (void*)out, D_, 2 * D_);

    (void)in_sizes; (void)n_in; (void)out_size; (void)ws_size;
}

// Round 11
// 774.291 us; speedup vs baseline: 2.6988x; 1.2131x over previous
//
#include <hip/hip_runtime.h>
#include <hip/hip_bf16.h>
#include <math.h>

#define B_ 4
#define N_ 2048
#define D_ 1024
#define WIN_ 4
#define KTOP 8
#define ALPHA_ 0.3f
#define SCALE_ (1.0f/32.0f)
#define NCH 16          // N_/128 col chunks
#define TROW 36         // ushorts per LDS tile row (72B stride, conflict-free)
#define TPLANE (128 * TROW)
#define INV2048 0.00048828125f

typedef unsigned short ushortT;
typedef _Float16 halfT;
typedef __attribute__((ext_vector_type(8))) _Float16 half8v;  // 8 fp16 (4 VGPR)
typedef __attribute__((ext_vector_type(4))) float f32x4;

__device__ inline ushortT h2u(halfT h){ union{halfT h; ushortT u;} x; x.h=h; return x.u; }
__device__ inline halfT  u2h(ushortT u){ union{halfT h; ushortT u;} x; x.u=u; return x.h; }
__device__ inline float  uh2f(ushortT u){ return (float)u2h(u); }

// ---------------------------------------------------------------------------
// mu f32 -> 2 fp16 planes: a = fp16(x), B = fp16((x - a) * 2048)  (scaled,
// always normal; x ≈ a + B/2048 to 2^-22 relative)
// ---------------------------------------------------------------------------
__global__ __launch_bounds__(256)
void split2_mu(const float* __restrict__ src, ushortT* __restrict__ Pa,
               ushortT* __restrict__ Pb)
{
    size_t base = ((size_t)blockIdx.x * 256 + threadIdx.x) * 4;
    float4 v = *reinterpret_cast<const float4*>(&src[base]);
    float vv[4] = {v.x, v.y, v.z, v.w};
    ushort4 pa, pb;
#pragma unroll
    for (int j = 0; j < 4; ++j) {
        float f = vv[j];
        halfT a = (halfT)f;  float r = f - (float)a;
        halfT b = (halfT)(r * 2048.0f);
        ((ushortT*)&pa)[j] = h2u(a); ((ushortT*)&pb)[j] = h2u(b);
    }
    *reinterpret_cast<ushort4*>(&Pa[base]) = pa;
    *reinterpret_cast<ushort4*>(&Pb[base]) = pb;
}

// ---------------------------------------------------------------------------
// W [K][Nn] f32 -> Wt [Nn][K] fp16 (single plane)
// ---------------------------------------------------------------------------
__global__ __launch_bounds__(256)
void transpose_f2h(const float* __restrict__ W, ushortT* __restrict__ Wt,
                   int K, int Nn)
{
    __shared__ float t[32][33];
    const int k0 = blockIdx.x * 32, n0 = blockIdx.y * 32;
    const int tx = threadIdx.x & 31, ty8 = threadIdx.x >> 5;
#pragma unroll
    for (int p = 0; p < 4; ++p) {
        int kk = p * 8 + ty8;
        t[kk][tx] = W[(size_t)(k0 + kk) * Nn + n0 + tx];
    }
    __syncthreads();
#pragma unroll
    for (int p = 0; p < 4; ++p) {
        int nn = p * 8 + ty8;
        Wt[(size_t)(n0 + nn) * K + k0 + tx] = h2u((halfT)t[tx][nn]);
    }
}

// ---------------------------------------------------------------------------
// W [K][Nn] f32 -> 2 transposed fp16 planes [Nn][K] (a, scaled-residual B)
// ---------------------------------------------------------------------------
__global__ __launch_bounds__(256)
void transpose_split2(const float* __restrict__ W, ushortT* __restrict__ Pa,
                      ushortT* __restrict__ Pb, int K, int Nn)
{
    __shared__ float t[32][33];
    const int k0 = blockIdx.x * 32, n0 = blockIdx.y * 32;
    const int tx = threadIdx.x & 31, ty8 = threadIdx.x >> 5;
#pragma unroll
    for (int p = 0; p < 4; ++p) {
        int kk = p * 8 + ty8;
        t[kk][tx] = W[(size_t)(k0 + kk) * Nn + n0 + tx];
    }
    __syncthreads();
#pragma unroll
    for (int p = 0; p < 4; ++p) {
        int nn = p * 8 + ty8;
        float f = t[tx][nn];
        halfT a = (halfT)f;  float r = f - (float)a;
        halfT b = (halfT)(r * 2048.0f);
        size_t o = (size_t)(n0 + nn) * K + k0 + tx;
        Pa[o] = h2u(a); Pb[o] = h2u(b);
    }
}

// ---------------------------------------------------------------------------
// fp16 MFMA GEMM (R5-proven structure, f16 dtype): 128x128 tile, BK=64,
// 4 waves, 64x64/wave. OUT_HALF: 1 = fp16 out, 0 = f32 out.
// ---------------------------------------------------------------------------
template<int OUT_HALF>
__global__ __launch_bounds__(256)
void mfma_gemm_h(const ushortT* __restrict__ A, int lda,
                 const ushortT* __restrict__ Bt, int ldb,
                 const float* __restrict__ bias,
                 void* __restrict__ Cout, int ldc, int K)
{
    __shared__ ushortT AsL[128 * 72];
    __shared__ ushortT BsL[128 * 72];
    const int tid = threadIdx.x;
    const int m0 = blockIdx.y * 128;
    const int n0 = blockIdx.x * 128;
    const int w = tid >> 6, lane = tid & 63;
    const int wr = w >> 1, wc = w & 1;

    f32x4 acc[4][4];
#pragma unroll
    for (int mi = 0; mi < 4; ++mi)
#pragma unroll
        for (int ni = 0; ni < 4; ++ni) acc[mi][ni] = (f32x4){0.f, 0.f, 0.f, 0.f};

    for (int k0 = 0; k0 < K; k0 += 64) {
#pragma unroll
        for (int it = 0; it < 4; ++it) {
            int idx = tid + it * 256;        // 0..1023
            int row = idx >> 3, c = idx & 7;
            int4 va = *reinterpret_cast<const int4*>(&A[(size_t)(m0 + row) * lda + k0 + c * 8]);
            *reinterpret_cast<int4*>(&AsL[row * 72 + c * 8]) = va;
            int4 vb = *reinterpret_cast<const int4*>(&Bt[(size_t)(n0 + row) * ldb + k0 + c * 8]);
            *reinterpret_cast<int4*>(&BsL[row * 72 + c * 8]) = vb;
        }
        __syncthreads();
#pragma unroll
        for (int kh = 0; kh < 2; ++kh) {
            const int ko = kh * 32 + (lane >> 4) * 8;
            const int rr = lane & 15;
            half8v af[4], bf[4];
#pragma unroll
            for (int mi = 0; mi < 4; ++mi)
                af[mi] = *reinterpret_cast<const half8v*>(&AsL[(wr * 64 + mi * 16 + rr) * 72 + ko]);
#pragma unroll
            for (int ni = 0; ni < 4; ++ni)
                bf[ni] = *reinterpret_cast<const half8v*>(&BsL[(wc * 64 + ni * 16 + rr) * 72 + ko]);
#pragma unroll
            for (int mi = 0; mi < 4; ++mi)
#pragma unroll
                for (int ni = 0; ni < 4; ++ni)
                    acc[mi][ni] = __builtin_amdgcn_mfma_f32_16x16x32_f16(
                        af[mi], bf[ni], acc[mi][ni], 0, 0, 0);
        }
        __syncthreads();
    }

    const int r4 = (lane >> 4) * 4, cl = lane & 15;
#pragma unroll
    for (int mi = 0; mi < 4; ++mi)
#pragma unroll
        for (int ni = 0; ni < 4; ++ni) {
            int row = m0 + wr * 64 + mi * 16 + r4;
            int col = n0 + wc * 64 + ni * 16 + cl;
            float bb = bias ? bias[col] : 0.f;
#pragma unroll
            for (int r = 0; r < 4; ++r) {
                float v = acc[mi][ni][r] + bb;
                if (OUT_HALF)
                    ((ushortT*)Cout)[(size_t)(row + r) * ldc + col] = h2u((halfT)v);
                else
                    ((float*)Cout)[(size_t)(row + r) * ldc + col] = v;
            }
        }
}

// ---------------------------------------------------------------------------
// S[b,n,:] = mean_w silu(A + Nb shifted), output fp16.
// ---------------------------------------------------------------------------
__global__ __launch_bounds__(256)
void silu_mean(const float* __restrict__ A, const float* __restrict__ Nb,
               ushortT* __restrict__ Sb)
{
    size_t idx4 = (size_t)blockIdx.x * blockDim.x + threadIdx.x;
    size_t base = idx4 << 2;
    int n = (int)((base >> 10) & (N_ - 1));
    float4 a = *reinterpret_cast<const float4*>(&A[base]);
    float sx = 0.f, sy = 0.f, sz = 0.f, sw = 0.f;
#pragma unroll
    for (int w = 1; w <= WIN_; ++w) {
        float xx = a.x, xy = a.y, xz = a.z, xw = a.w;
        if (n >= w) {
            const float4 nb = *reinterpret_cast<const float4*>(&Nb[base - (size_t)w * D_]);
            xx += nb.x; xy += nb.y; xz += nb.z; xw += nb.w;
        }
        sx += xx / (1.f + __expf(-xx));
        sy += xy / (1.f + __expf(-xy));
        sz += xz / (1.f + __expf(-xz));
        sw += xw / (1.f + __expf(-xw));
    }
    ushort4 o = {h2u((halfT)(sx * 0.25f)), h2u((halfT)(sy * 0.25f)),
                 h2u((halfT)(sz * 0.25f)), h2u((halfT)(sw * 0.25f))};
    *reinterpret_cast<ushort4*>(&Sb[base]) = o;
}

// ---------------------------------------------------------------------------
__device__ inline void topk_insert(float (&tv)[KTOP], int (&ti)[KTOP], float s, int m)
{
    if ((s > tv[KTOP-1]) || (s == tv[KTOP-1] && m < ti[KTOP-1])) {
        float cs = s; int ci = m;
#pragma unroll
        for (int q = 0; q < KTOP; ++q) {
            bool beats = (cs > tv[q]) || (cs == tv[q] && ci < ti[q]);
            if (beats) { float t0 = tv[q]; int t1 = ti[q];
                         tv[q] = cs; ti[q] = ci; cs = t0; ci = t1; }
        }
    }
}

// ---------------------------------------------------------------------------
// fp16 2-plane 3-product core: planes {Aa, AB} x {Ba, BB}, products
// Aa*Ba -> acc0 ; Aa*BB + AB*Ba -> acc1 ; result = acc0 + acc1/2048.
// 8 waves, wave tile 64x32 (wr in {0,1}, wc in {0..3}), acc[4][2] x 2 sets.
// Phase-split A-plane loops keep <=4 A-frags live (VGPR control, R8 lesson).
// ---------------------------------------------------------------------------
#define SPLIT3H_COMPUTE(T4, wr, wc, lane, acc0, acc1)                           \
    {                                                                           \
        const int rr_ = (lane) & 15, ko_ = ((lane) >> 4) * 8;                   \
        half8v ba0_ = *reinterpret_cast<const half8v*>(                         \
            &T4[2 * TPLANE + ((wc) * 32 + rr_) * TROW + ko_]);                  \
        half8v ba1_ = *reinterpret_cast<const half8v*>(                         \
            &T4[2 * TPLANE + ((wc) * 32 + 16 + rr_) * TROW + ko_]);             \
        half8v bB0_ = *reinterpret_cast<const half8v*>(                         \
            &T4[3 * TPLANE + ((wc) * 32 + rr_) * TROW + ko_]);                  \
        half8v bB1_ = *reinterpret_cast<const half8v*>(                         \
            &T4[3 * TPLANE + ((wc) * 32 + 16 + rr_) * TROW + ko_]);             \
        _Pragma("unroll")                                                       \
        for (int mi_ = 0; mi_ < 4; ++mi_) {                                     \
            half8v aA_ = *reinterpret_cast<const half8v*>(                      \
                &T4[0 * TPLANE + ((wr) * 64 + mi_ * 16 + rr_) * TROW + ko_]);   \
            acc0[mi_][0] = __builtin_amdgcn_mfma_f32_16x16x32_f16(              \
                aA_, ba0_, acc0[mi_][0], 0, 0, 0);                              \
            acc0[mi_][1] = __builtin_amdgcn_mfma_f32_16x16x32_f16(              \
                aA_, ba1_, acc0[mi_][1], 0, 0, 0);                              \
            acc1[mi_][0] = __builtin_amdgcn_mfma_f32_16x16x32_f16(              \
                aA_, bB0_, acc1[mi_][0], 0, 0, 0);                              \
            acc1[mi_][1] = __builtin_amdgcn_mfma_f32_16x16x32_f16(              \
                aA_, bB1_, acc1[mi_][1], 0, 0, 0);                              \
        }                                                                       \
        _Pragma("unroll")                                                       \
        for (int mi_ = 0; mi_ < 4; ++mi_) {                                     \
            half8v aB_ = *reinterpret_cast<const half8v*>(                      \
                &T4[1 * TPLANE + ((wr) * 64 + mi_ * 16 + rr_) * TROW + ko_]);   \
            acc1[mi_][0] = __builtin_amdgcn_mfma_f32_16x16x32_f16(              \
                aB_, ba0_, acc1[mi_][0], 0, 0, 0);                              \
            acc1[mi_][1] = __builtin_amdgcn_mfma_f32_16x16x32_f16(              \
                aB_, ba1_, acc1[mi_][1], 0, 0, 0);                              \
        }                                                                       \
    }

// ---------------------------------------------------------------------------
// gemm_split3h: out = (Aa + AB/2048) @ (Ba + BB/2048)^T + bias, 3 kept
// products (f32-equivalent to 2^-22). Output split into 2 fp16 planes.
// 512 thr, 8 waves, BK=32, reg-prefetch, XCD swizzle. (R7 envelope.)
// ---------------------------------------------------------------------------
__global__ __launch_bounds__(512, 4)
void gemm_split3h(const ushortT* __restrict__ A0, const ushortT* __restrict__ A1,
                  const ushortT* __restrict__ B0, const ushortT* __restrict__ B1,
                  const float* __restrict__ bias,
                  ushortT* __restrict__ Pa, ushortT* __restrict__ Pb)
{
    __shared__ ushortT T4[4 * TPLANE];     // 36864 B

    int lin = blockIdx.y * 8 + blockIdx.x;                // 0..511
    lin = (lin & 7) * 64 + (lin >> 3);                    // XCD-chunked
    const int m0 = (lin >> 3) * 128;
    const int n0 = (lin & 7) * 128;

    const int tid = threadIdx.x;
    const int wid = tid >> 6, lane = tid & 63;
    const int wr = wid >> 2, wc = wid & 3;
    const int rowL = tid >> 2, cL = tid & 3;

    const size_t offA = (size_t)(m0 + rowL) * D_ + cL * 8;
    const size_t offB = (size_t)(n0 + rowL) * D_ + cL * 8;
    const int ldst = rowL * TROW + cL * 8;

    f32x4 acc0[4][2], acc1[4][2];
#pragma unroll
    for (int mi = 0; mi < 4; ++mi) {
        acc0[mi][0] = (f32x4){0,0,0,0}; acc0[mi][1] = (f32x4){0,0,0,0};
        acc1[mi][0] = (f32x4){0,0,0,0}; acc1[mi][1] = (f32x4){0,0,0,0};
    }

    int4 s0, s1, s2, s3;
    s0 = *reinterpret_cast<const int4*>(&A0[offA]);
    s1 = *reinterpret_cast<const int4*>(&A1[offA]);
    s2 = *reinterpret_cast<const int4*>(&B0[offB]);
    s3 = *reinterpret_cast<const int4*>(&B1[offB]);

    for (int ks = 0; ks < 32; ++ks) {
        __syncthreads();
        *reinterpret_cast<int4*>(&T4[0 * TPLANE + ldst]) = s0;
        *reinterpret_cast<int4*>(&T4[1 * TPLANE + ldst]) = s1;
        *reinterpret_cast<int4*>(&T4[2 * TPLANE + ldst]) = s2;
        *reinterpret_cast<int4*>(&T4[3 * TPLANE + ldst]) = s3;
        __syncthreads();
        if (ks < 31) {
            const int kk = (ks + 1) * 32;
            s0 = *reinterpret_cast<const int4*>(&A0[offA + kk]);
            s1 = *reinterpret_cast<const int4*>(&A1[offA + kk]);
            s2 = *reinterpret_cast<const int4*>(&B0[offB + kk]);
            s3 = *reinterpret_cast<const int4*>(&B1[offB + kk]);
        }
        SPLIT3H_COMPUTE(T4, wr, wc, lane, acc0, acc1)
    }

    const int r4 = (lane >> 4) * 4, cl = lane & 15;
#pragma unroll
    for (int mi = 0; mi < 4; ++mi)
#pragma unroll
        for (int ni = 0; ni < 2; ++ni) {
            int col = n0 + wc * 32 + ni * 16 + cl;
            float bb = bias[col];
#pragma unroll
            for (int r = 0; r < 4; ++r) {
                int row = m0 + wr * 64 + mi * 16 + r4 + r;
                float v = acc0[mi][ni][r] + INV2048 * acc1[mi][ni][r] + bb;
                halfT a = (halfT)v;  float r1 = v - (float)a;
                halfT b = (halfT)(r1 * 2048.0f);
                size_t o = (size_t)row * D_ + col;
                Pa[o] = h2u(a); Pb[o] = h2u(b);
            }
        }
}

// ---------------------------------------------------------------------------
// attn_scores_h: fp16 2-plane split scores + mask + pheromone + per-chunk
// top-8. 512 thr, 8 waves, BK=32, reg-prefetch, XCD swizzle. (R7 envelope.)
// ---------------------------------------------------------------------------
__global__ __launch_bounds__(512, 4)
void attn_scores_h(const ushortT* __restrict__ Qa, const ushortT* __restrict__ QB,
                   const ushortT* __restrict__ Ka, const ushortT* __restrict__ KB,
                   const float* __restrict__ pher,
                   float* __restrict__ WV, int* __restrict__ WI)
{
    __shared__ ushortT T4[4 * TPLANE];     // 36864 B
    __shared__ float Ps[128];
    __shared__ float PV[32 * 4 * 8];
    __shared__ int   PI[32 * 4 * 8];
    float* MV = reinterpret_cast<float*>(&T4[0]);                    // [32][128]
    int*   MI = reinterpret_cast<int*>((char*)&T4[0] + 16384);       // [32][128]

    int lin = blockIdx.y * 136 + blockIdx.x;              // 0..543
    lin = (lin & 7) * 68 + (lin >> 3);                    // XCD-chunked, 544=8*68
    const int b = lin / 136;
    const int xy = lin - b * 136;
    int g = 0;
    while ((g + 1) * (g + 2) / 2 <= xy) ++g;
    const int ch = xy - g * (g + 1) / 2;
    const int n0 = g * 128;
    const int m0 = ch * 128;
    const size_t bN = (size_t)b * N_;

    const int tid = threadIdx.x;
    const int wid = tid >> 6, lane = tid & 63;
    const int wr = wid >> 2, wc = wid & 3;
    const int rowL = tid >> 2, cL = tid & 3;

    if (tid < 128) Ps[tid] = pher[bN + m0 + tid];

    const size_t offQ = (bN + n0 + rowL) * (size_t)D_ + cL * 8;
    const size_t offK = (bN + m0 + rowL) * (size_t)D_ + cL * 8;
    const int ldst = rowL * TROW + cL * 8;

    f32x4 acc0[4][2], acc1[4][2];
#pragma unroll
    for (int mi = 0; mi < 4; ++mi) {
        acc0[mi][0] = (f32x4){0,0,0,0}; acc0[mi][1] = (f32x4){0,0,0,0};
        acc1[mi][0] = (f32x4){0,0,0,0}; acc1[mi][1] = (f32x4){0,0,0,0};
    }

    int4 s0, s1, s2, s3;
    s0 = *reinterpret_cast<const int4*>(&Qa[offQ]);
    s1 = *reinterpret_cast<const int4*>(&QB[offQ]);
    s2 = *reinterpret_cast<const int4*>(&Ka[offK]);
    s3 = *reinterpret_cast<const int4*>(&KB[offK]);

    for (int ks = 0; ks < 32; ++ks) {
        __syncthreads();
        *reinterpret_cast<int4*>(&T4[0 * TPLANE + ldst]) = s0;
        *reinterpret_cast<int4*>(&T4[1 * TPLANE + ldst]) = s1;
        *reinterpret_cast<int4*>(&T4[2 * TPLANE + ldst]) = s2;
        *reinterpret_cast<int4*>(&T4[3 * TPLANE + ldst]) = s3;
        __syncthreads();
        if (ks < 31) {
            const int kk = (ks + 1) * 32;
            s0 = *reinterpret_cast<const int4*>(&Qa[offQ + kk]);
            s1 = *reinterpret_cast<const int4*>(&QB[offQ + kk]);
            s2 = *reinterpret_cast<const int4*>(&Ka[offK + kk]);
            s3 = *reinterpret_cast<const int4*>(&KB[offK + kk]);
        }
        SPLIT3H_COMPUTE(T4, wr, wc, lane, acc0, acc1)
    }

    // ---- fold to per-row top-8: 4 passes of 32 rows (R7-proven) ----
    const int r4 = (lane >> 4) * 4, cl = lane & 15;
    for (int p = 0; p < 4; ++p) {
        __syncthreads();                       // T4/MV consumers done
        if (wr == (p >> 1)) {
#pragma unroll
            for (int mi2 = 0; mi2 < 2; ++mi2) {
                const int mi = (p & 1) * 2 + mi2;
#pragma unroll
                for (int ni = 0; ni < 2; ++ni) {
                    int col = wc * 32 + ni * 16 + cl;
                    int m = m0 + col;
#pragma unroll
                    for (int r = 0; r < 4; ++r) {
                        int rloc = mi2 * 16 + r4 + r;
                        int n = n0 + p * 32 + rloc;
                        bool ok = (m <= n);
                        float sc = acc0[mi][ni][r] + INV2048 * acc1[mi][ni][r];
                        MV[rloc * 128 + col] = ok ? (sc * SCALE_ + ALPHA_ * Ps[col])
                                                  : -INFINITY;
                        MI[rloc * 128 + col] = ok ? m : 0x7fffffff;
                    }
                }
            }
        }
        __syncthreads();
        if (tid < 128) {                       // partial top-8 over a 32-col quarter
            const int row = tid >> 2, q4 = tid & 3;
            float tv[KTOP]; int ti[KTOP];
#pragma unroll
            for (int j = 0; j < KTOP; ++j) { tv[j] = -INFINITY; ti[j] = 0x7fffffff; }
            for (int j = 0; j < 32; ++j) {
                float s2 = MV[row * 128 + q4 * 32 + j];
                if (s2 == -INFINITY) continue;
                topk_insert(tv, ti, s2, MI[row * 128 + q4 * 32 + j]);
            }
#pragma unroll
            for (int j = 0; j < KTOP; ++j) {
                PV[(row * 4 + q4) * 8 + j] = tv[j];
                PI[(row * 4 + q4) * 8 + j] = ti[j];
            }
        }
        __syncthreads();
        if (tid < 32) {                        // merge 4 partials -> chunk top-8
            float tv[KTOP]; int ti[KTOP];
#pragma unroll
            for (int j = 0; j < KTOP; ++j) { tv[j] = -INFINITY; ti[j] = 0x7fffffff; }
            for (int i = 0; i < 32; ++i) {
                float s2 = PV[tid * 32 + i];
                if (s2 == -INFINITY) continue;
                topk_insert(tv, ti, s2, PI[tid * 32 + i]);
            }
            int n = n0 + p * 32 + tid;
            size_t base = ((bN + n) * NCH + ch) * 8;
#pragma unroll
            for (int j = 0; j < KTOP; ++j) { WV[base + j] = tv[j]; WI[base + j] = ti[j]; }
        }
    }
}

// ---------------------------------------------------------------------------
// attn_merge: merge <=16 chunk lists -> top-8 -> softmax -> gather fp16 V ->
// CCb right half (fp16). Grid 2048 blocks, 4 rows each.
// ---------------------------------------------------------------------------
__global__ __launch_bounds__(256)
void attn_merge(const float* __restrict__ WV, const int* __restrict__ WI,
                const ushortT* __restrict__ V, ushortT* __restrict__ CCb)
{
    __shared__ float CV[4][128];
    __shared__ int   CI[4][128];
    __shared__ float Pp[4][KTOP];
    __shared__ int   Pi[4][KTOP];

    const int tid  = threadIdx.x;
    const int wv   = tid >> 6;
    const int lane = tid & 63;
    const int rid  = blockIdx.x * 4 + wv;
    const int b    = rid >> 11;
    const int n    = rid & (N_ - 1);
    const int ncand = ((n >> 7) + 1) * 8;
    const size_t cbase = (size_t)rid * (NCH * 8);

#pragma unroll
    for (int t = 0; t < 2; ++t) {
        int i = lane + t * 64;
        if (i < ncand) { CV[wv][i] = WV[cbase + i]; CI[wv][i] = WI[cbase + i]; }
        else           { CV[wv][i] = -INFINITY;     CI[wv][i] = 0x7fffffff;   }
    }
    __syncthreads();

    if (lane == 0) {
        float tv[KTOP]; int ti[KTOP];
#pragma unroll
        for (int j = 0; j < KTOP; ++j) { tv[j] = -INFINITY; ti[j] = 0x7fffffff; }
        for (int i = 0; i < 128; ++i) {
            float s = CV[wv][i];
            if (s == -INFINITY) continue;
            topk_insert(tv, ti, s, CI[wv][i]);
        }
        float mx = tv[0];
        float e[KTOP]; float sum = 0.f;
#pragma unroll
        for (int j = 0; j < KTOP; ++j) {
            e[j] = (tv[j] == -INFINITY) ? 0.f : __expf(tv[j] - mx);
            sum += e[j];
        }
        float inv = 1.f / sum;
#pragma unroll
        for (int j = 0; j < KTOP; ++j) {
            Pp[wv][j] = e[j] * inv;
            Pi[wv][j] = (tv[j] == -INFINITY) ? 0 : ti[j];
        }
    }
    __syncthreads();

    const size_t vbase = (size_t)b * N_ * D_;
#pragma unroll
    for (int it = 0; it < 2; ++it) {
        int c8 = (it * 64 + lane) * 8;
        float o[8];
#pragma unroll
        for (int u = 0; u < 8; ++u) o[u] = 0.f;
#pragma unroll
        for (int j = 0; j < KTOP; ++j) {
            float p = Pp[wv][j];
            ushort4 v0 = *reinterpret_cast<const ushort4*>(
                &V[vbase + (size_t)Pi[wv][j] * D_ + c8]);
            ushort4 v1 = *reinterpret_cast<const ushort4*>(
                &V[vbase + (size_t)Pi[wv][j] * D_ + c8 + 4]);
            o[0] = fmaf(p, uh2f(v0.x), o[0]); o[1] = fmaf(p, uh2f(v0.y), o[1]);
            o[2] = fmaf(p, uh2f(v0.z), o[2]); o[3] = fmaf(p, uh2f(v0.w), o[3]);
            o[4] = fmaf(p, uh2f(v1.x), o[4]); o[5] = fmaf(p, uh2f(v1.y), o[5]);
            o[6] = fmaf(p, uh2f(v1.z), o[6]); o[7] = fmaf(p, uh2f(v1.w), o[7]);
        }
        ushort4 ob0 = {h2u((halfT)o[0]), h2u((halfT)o[1]), h2u((halfT)o[2]), h2u((halfT)o[3])};
        ushort4 ob1 = {h2u((halfT)o[4]), h2u((halfT)o[5]), h2u((halfT)o[6]), h2u((halfT)o[7])};
        *reinterpret_cast<ushort4*>(&CCb[(size_t)rid * 2048 + 1024 + c8]) = ob0;
        *reinterpret_cast<ushort4*>(&CCb[(size_t)rid * 2048 + 1024 + c8 + 4]) = ob1;
    }
}

// ---------------------------------------------------------------------------
extern "C" void kernel_launch(void* const* d_in, const int* in_sizes, int n_in,
                              void* d_out, int out_size, void* d_ws, size_t ws_size,
                              hipStream_t stream)
{
    const float* mu   = (const float*)d_in[0];
    const float* pher = (const float*)d_in[1];
    const float* Wq   = (const float*)d_in[2];
    const float* bq   = (const float*)d_in[3];
    const float* Wk   = (const float*)d_in[4];
    const float* bk   = (const float*)d_in[5];
    const float* Wv   = (const float*)d_in[6];
    const float* bv   = (const float*)d_in[7];
    const float* Wm1  = (const float*)d_in[8];
    const float* bm1  = (const float*)d_in[9];
    const float* Wm2  = (const float*)d_in[10];
    const float* bm2  = (const float*)d_in[11];
    const float* Wo   = (const float*)d_in[12];
    const float* bo   = (const float*)d_in[13];
    float* out = (float*)d_out;
    float* ws  = (float*)d_ws;

    const size_t SZ  = (size_t)B_ * N_ * D_;    // 8388608 floats
    const size_t MEG = 1024 * 1024;             // floats
    const int M = B_ * N_;                      // 8192

    // ---- workspace map (float units), total 4.5*SZ + 7*MEG ≈ 179 MB ----
    ushortT* CCb  = (ushortT*)ws;                         // [8192][2048] fp16
    float*   AbF  = ws + SZ;                              // f32 pre-act (phase 1)
    float*   NbF  = ws + 2 * SZ;
    ushortT* Qa   = (ushortT*)(ws + SZ);                  // overlay after silu
    ushortT* QB   = Qa + SZ;
    ushortT* Ka   = (ushortT*)(ws + 2 * SZ);
    ushortT* KB   = Ka + SZ;
    ushortT* mu_a = (ushortT*)(ws + 3 * SZ);              // fp16 plane (SZ ushorts)
    ushortT* mu_B = mu_a + SZ;                            // scaled residual plane
    ushortT* Sb   = (ushortT*)(ws + 4 * SZ);              // fp16 S; dead after local gemm
    float*   WVb  = (float*)(ws + 4 * SZ);                // overlay Sb after local gemm
    int*     WIb  = (int*)(WVb + MEG);
    ushortT* Vb16 = (ushortT*)(ws + 4 * SZ + 2 * MEG);    // fp16 V (SZ ushorts)
    ushortT* U    = (ushortT*)(ws + 4 * SZ + 2 * MEG + SZ / 2);   // weights (10M ush)
    ushortT* Wt_m1 = U;                  // [1024][2048] = 2M ush
    ushortT* Wt_m2 = U + 2 * MEG;        // [1024][1024] = 1M ush
    ushortT* Wt_v  = U + 3 * MEG;        // 1M ush
    ushortT* WqT_a = U + 4 * MEG;        ushortT* WqT_B = U + 5 * MEG;
    ushortT* WkT_a = U + 6 * MEG;        ushortT* WkT_B = U + 7 * MEG;
    ushortT* Wt_o  = U + 8 * MEG;        // [1024][2048] = 2M ush

    dim3 blk256(256), blk512(512);
    dim3 gD(8, 64);

    // 1. mu -> 2 fp16 planes
    hipLaunchKernelGGL(split2_mu, dim3(SZ / 4 / 256), blk256, 0, stream, mu, mu_a, mu_B);
    // 2. weight transposes
    hipLaunchKernelGGL(transpose_f2h, dim3(64, 32), blk256, 0, stream, Wm1, Wt_m1, 2048, 1024);
    hipLaunchKernelGGL(transpose_f2h, dim3(32, 32), blk256, 0, stream, Wm2, Wt_m2, 1024, 1024);
    hipLaunchKernelGGL(transpose_f2h, dim3(32, 32), blk256, 0, stream, Wv, Wt_v, 1024, 1024);
    hipLaunchKernelGGL(transpose_f2h, dim3(64, 32), blk256, 0, stream, Wo, Wt_o, 2048, 1024);
    hipLaunchKernelGGL(transpose_split2, dim3(32, 32), blk256, 0, stream,
                       Wq, WqT_a, WqT_B, 1024, 1024);
    hipLaunchKernelGGL(transpose_split2, dim3(32, 32), blk256, 0, stream,
                       Wk, WkT_a, WkT_B, 1024, 1024);
    // 3-4. local pre-acts (fp16 MFMA, f32 out)
    hipLaunchKernelGGL((mfma_gemm_h<0>), gD, blk256, 0, stream,
                       mu_a, D_, Wt_m1, 2048, bm1, (void*)AbF, D_, D_);
    hipLaunchKernelGGL((mfma_gemm_h<0>), gD, blk256, 0, stream,
                       mu_a, D_, Wt_m1 + 1024, 2048, (const float*)nullptr, (void*)NbF, D_, D_);
    // 5. silu-mean -> Sb (fp16)
    hipLaunchKernelGGL(silu_mean, dim3(SZ / 4 / 256), blk256, 0, stream, AbF, NbF, Sb);
    // 6. local msgs -> CCb left half (fp16)
    hipLaunchKernelGGL((mfma_gemm_h<1>), gD, blk256, 0, stream,
                       Sb, D_, Wt_m2, D_, bm2, (void*)CCb, 2 * D_, D_);
    // 7. V -> fp16
    hipLaunchKernelGGL((mfma_gemm_h<1>), gD, blk256, 0, stream,
                       mu_a, D_, Wt_v, D_, bv, (void*)Vb16, D_, D_);
    // 8-9. Q/K projections (fp16 split-MFMA, f32-equivalent) -> 2 planes each
    hipLaunchKernelGGL(gemm_split3h, gD, blk512, 0, stream,
                       mu_a, mu_B, WqT_a, WqT_B, bq, Qa, QB);
    hipLaunchKernelGGL(gemm_split3h, gD, blk512, 0, stream,
                       mu_a, mu_B, WkT_a, WkT_B, bk, Ka, KB);
    // 10. scores + per-chunk top-8
    hipLaunchKernelGGL(attn_scores_h, dim3(136, B_), blk512, 0, stream,
                       Qa, QB, Ka, KB, pher, WVb, WIb);
    // 11. merge + softmax + V gather -> CCb right half
    hipLaunchKernelGGL(attn_merge, dim3(M / 4), blk256, 0, stream, WVb, WIb, Vb16, CCb);
    // 12. out = CCb @ Wo + bo (fp16 MFMA, K=2048, f32 out)
    hipLaunchKernelGGL((mfma_gemm_h<0>), gD, blk256, 0, stream,
                       CCb, 2 * D_, Wt_o, 2048, bo, (void*)out, D_, 2 * D_);

    (void)in_sizes; (void)n_in; (void)out_size; (void)ws_size;
}